// Round 1
// baseline (495.319 us; speedup 1.0000x reference)
//
#include <hip/hip_runtime.h>
#include <stdint.h>

typedef __attribute__((ext_vector_type(8))) short bf16x8;
typedef __attribute__((ext_vector_type(4))) float f32x4;

#define GLOBAL_AS __attribute__((address_space(1)))
#define LDS_AS    __attribute__((address_space(3)))

__device__ __forceinline__ void load_lds16(const void* g, void* l) {
  __builtin_amdgcn_global_load_lds((const GLOBAL_AS void*)g, (LDS_AS void*)l, 16, 0, 0);
}

__device__ __forceinline__ float bf2f(short s) {
  return __uint_as_float(((unsigned)(unsigned short)s) << 16);
}
__device__ __forceinline__ short f2bf(float f) {
  unsigned u = __float_as_uint(f);
  u += 0x7fffu + ((u >> 16) & 1u);
  return (short)(u >> 16);
}

// ---------------- fp32 -> bf16 convert (vectorized) ----------------
__global__ __launch_bounds__(256) void cvt_bf16(const float* __restrict__ in,
                                                short* __restrict__ out, int n) {
  int i = (blockIdx.x * 256 + threadIdx.x) * 8;
  if (i >= n) return;
  float4 a = *(const float4*)(in + i);
  float4 b = *(const float4*)(in + i + 4);
  bf16x8 o;
  o[0] = f2bf(a.x); o[1] = f2bf(a.y); o[2] = f2bf(a.z); o[3] = f2bf(a.w);
  o[4] = f2bf(b.x); o[5] = f2bf(b.y); o[6] = f2bf(b.z); o[7] = f2bf(b.w);
  *(bf16x8*)(out + i) = o;
}

// ---------------- C = A * B^T  (A:[M,K] bf16, B:[N,K] bf16) ----------------
// 128x128 tile, BK=64, 4 waves (2x2), each wave 64x64 via 4x4 frags of 16x16x32.
template<int OUT_BF16>
__global__ __launch_bounds__(256) void gemm_bt(const short* __restrict__ A,
                                               const short* __restrict__ B,
                                               void* __restrict__ Cp,
                                               int M, int N, int K) {
  __shared__ short As[128 * 64];
  __shared__ short Bs[128 * 64];
  const int t = threadIdx.x, l = t & 63, w = t >> 6;
  const int g = l >> 4, li = l & 15;
  const int wr = w >> 1, wc = w & 1;
  const int bm = blockIdx.x, bn = blockIdx.y;
  f32x4 acc[4][4] = {};
  const size_t arow0 = (size_t)(bm * 128) * K;
  const size_t brow0 = (size_t)(bn * 128) * K;
  for (int k0 = 0; k0 < K; k0 += 64) {
    __syncthreads();
#pragma unroll
    for (int it = 0; it < 4; ++it) {
      int e = it * 2048 + t * 8;
      int r = e >> 6, c = e & 63;
      load_lds16(A + arow0 + (size_t)r * K + (k0 + c), &As[e]);
      load_lds16(B + brow0 + (size_t)r * K + (k0 + c), &Bs[e]);
    }
    __syncthreads();
#pragma unroll
    for (int kk = 0; kk < 2; ++kk) {
      bf16x8 af[4], bfr[4];
#pragma unroll
      for (int m = 0; m < 4; ++m)
        af[m] = *(const bf16x8*)&As[(wr * 64 + m * 16 + li) * 64 + kk * 32 + g * 8];
#pragma unroll
      for (int n = 0; n < 4; ++n)
        bfr[n] = *(const bf16x8*)&Bs[(wc * 64 + n * 16 + li) * 64 + kk * 32 + g * 8];
#pragma unroll
      for (int m = 0; m < 4; ++m)
#pragma unroll
        for (int n = 0; n < 4; ++n)
          acc[m][n] = __builtin_amdgcn_mfma_f32_16x16x32_bf16(af[m], bfr[n], acc[m][n], 0, 0, 0);
    }
  }
#pragma unroll
  for (int m = 0; m < 4; ++m)
#pragma unroll
    for (int n = 0; n < 4; ++n)
#pragma unroll
      for (int r = 0; r < 4; ++r) {
        int row = bm * 128 + wr * 64 + m * 16 + g * 4 + r;
        int col = bn * 128 + wc * 64 + n * 16 + li;
        if (OUT_BF16)
          ((short*)Cp)[(size_t)row * N + col] = f2bf(acc[m][n][r]);
        else
          ((float*)Cp)[(size_t)row * N + col] = acc[m][n][r];
      }
}

// ---------------- flash attention ----------------
// qkv: [8192 tokens][3072] bf16 (cols: 0..1023=Q feat, 1024..2047=K, 2048..3071=V)
// obuf: [8192][1024] bf16
__global__ __launch_bounds__(256) void attn_fwd(const short* __restrict__ qkv,
                                                short* __restrict__ obuf) {
  const int qt = blockIdx.x;   // 0..31 : 64-row Q tile
  const int bh = blockIdx.y;   // 0..63 : b*16+h
  const int b = bh >> 4, h = bh & 15;
  const int t = threadIdx.x, w = t >> 6, l = t & 63;
  const int g = l >> 4, li = l & 15;

  __shared__ short Ks[64 * 64];      // K tile [key][d]
  __shared__ short Vt[64 * 72];      // V^T tile [d][key], stride 72
  __shared__ short Ps[4][16 * 72];   // per-wave P [q][key], stride 72

  const size_t base = (size_t)b * 2048 * 3072 + (size_t)h * 64;

  // Q fragments, pre-scaled by 1/sqrt(64)=0.125 (exact in bf16)
  const int qrow = qt * 64 + w * 16 + li;
  bf16x8 qf[2];
  {
    const short* qp = qkv + base + (size_t)qrow * 3072;
#pragma unroll
    for (int c = 0; c < 2; ++c) {
      bf16x8 v = *(const bf16x8*)(qp + c * 32 + g * 8);
#pragma unroll
      for (int i = 0; i < 8; ++i) v[i] = f2bf(bf2f(v[i]) * 0.125f);
      qf[c] = v;
    }
  }

  float m_[4], l_[4];
  f32x4 o_[4];
#pragma unroll
  for (int r = 0; r < 4; ++r) { m_[r] = -1e30f; l_[r] = 0.f; }
#pragma unroll
  for (int dj = 0; dj < 4; ++dj) o_[dj] = (f32x4){0.f, 0.f, 0.f, 0.f};

  for (int kt = 0; kt < 32; ++kt) {
    __syncthreads();   // previous tile's LDS reads done
    // stage K tile via global_load_lds
#pragma unroll
    for (int it = 0; it < 2; ++it) {
      int e = it * 2048 + t * 8;
      int r = e >> 6, c = e & 63;
      load_lds16(qkv + base + 1024 + (size_t)(kt * 64 + r) * 3072 + c, &Ks[e]);
    }
    // stage V^T via register transpose
#pragma unroll
    for (int it = 0; it < 2; ++it) {
      int e = it * 2048 + t * 8;
      int r = e >> 6, c = e & 63;
      bf16x8 v = *(const bf16x8*)(qkv + base + 2048 + (size_t)(kt * 64 + r) * 3072 + c);
#pragma unroll
      for (int i = 0; i < 8; ++i) Vt[(c + i) * 72 + r] = v[i];
    }
    __syncthreads();

    // S = (Q/8) K^T  -> C-layout: row q=g*4+r, col key=j*16+li
    f32x4 s_[4];
#pragma unroll
    for (int j = 0; j < 4; ++j) s_[j] = (f32x4){0.f, 0.f, 0.f, 0.f};
#pragma unroll
    for (int c = 0; c < 2; ++c)
#pragma unroll
      for (int j = 0; j < 4; ++j) {
        bf16x8 kf = *(const bf16x8*)&Ks[(j * 16 + li) * 64 + c * 32 + g * 8];
        s_[j] = __builtin_amdgcn_mfma_f32_16x16x32_bf16(qf[c], kf, s_[j], 0, 0, 0);
      }

    // online softmax per q-row
    float mt[4];
#pragma unroll
    for (int r = 0; r < 4; ++r) {
      float v = s_[0][r];
#pragma unroll
      for (int j = 1; j < 4; ++j) v = fmaxf(v, s_[j][r]);
#pragma unroll
      for (int d = 1; d < 16; d <<= 1) v = fmaxf(v, __shfl_xor(v, d));
      mt[r] = v;
    }
    float al[4], rs[4];
#pragma unroll
    for (int r = 0; r < 4; ++r) {
      float mn = fmaxf(m_[r], mt[r]);
      al[r] = __expf(m_[r] - mn);
      m_[r] = mn;
      rs[r] = 0.f;
    }
#pragma unroll
    for (int j = 0; j < 4; ++j)
#pragma unroll
      for (int r = 0; r < 4; ++r) {
        float p = __expf(s_[j][r] - m_[r]);
        s_[j][r] = p;
        rs[r] += p;
      }
#pragma unroll
    for (int r = 0; r < 4; ++r) {
#pragma unroll
      for (int d = 1; d < 16; d <<= 1) rs[r] += __shfl_xor(rs[r], d);
      l_[r] = l_[r] * al[r] + rs[r];
    }
#pragma unroll
    for (int dj = 0; dj < 4; ++dj)
#pragma unroll
      for (int r = 0; r < 4; ++r) o_[dj][r] *= al[r];

    // P -> LDS (per-wave region)
#pragma unroll
    for (int j = 0; j < 4; ++j)
#pragma unroll
      for (int r = 0; r < 4; ++r)
        Ps[w][(g * 4 + r) * 72 + j * 16 + li] = f2bf(s_[j][r]);
    __syncthreads();

    // O += P V   (A = P [q][k] from Ps, B[k][d] = Vt[d][k])
#pragma unroll
    for (int c = 0; c < 2; ++c) {
      bf16x8 pa = *(const bf16x8*)&Ps[w][li * 72 + c * 32 + g * 8];
#pragma unroll
      for (int dj = 0; dj < 4; ++dj) {
        bf16x8 vb = *(const bf16x8*)&Vt[(dj * 16 + li) * 72 + c * 32 + g * 8];
        o_[dj] = __builtin_amdgcn_mfma_f32_16x16x32_bf16(pa, vb, o_[dj], 0, 0, 0);
      }
    }
  }

  // epilogue: divide by softmax denom, store bf16
#pragma unroll
  for (int r = 0; r < 4; ++r) {
    float inv = 1.f / l_[r];
#pragma unroll
    for (int dj = 0; dj < 4; ++dj) {
      int row = b * 2048 + qt * 64 + w * 16 + g * 4 + r;
      int col = h * 64 + dj * 16 + li;
      obuf[(size_t)row * 1024 + col] = f2bf(o_[dj][r] * inv);
    }
  }
}

// ---------------- residual + LayerNorm (fp32) ----------------
__global__ __launch_bounds__(256) void resid_ln(const float* __restrict__ U,
                                                const float* __restrict__ x,
                                                const float* __restrict__ gamma,
                                                const float* __restrict__ beta,
                                                float* __restrict__ out) {
  const int row = blockIdx.x;
  const int t = threadIdx.x, w = t >> 6, l = t & 63;
  const float* u = U + (size_t)row * 1024;
  const float* xr = x + (size_t)row * 1024;
  float y[4];
  float s = 0.f;
#pragma unroll
  for (int i = 0; i < 4; ++i) {
    int c = t + i * 256;
    y[i] = u[c] + xr[c];
    s += y[i];
  }
#pragma unroll
  for (int d = 1; d < 64; d <<= 1) s += __shfl_xor(s, d);
  __shared__ float red[4];
  if (l == 0) red[w] = s;
  __syncthreads();
  s = red[0] + red[1] + red[2] + red[3];
  const float mu = s * (1.f / 1024.f);
  float vs = 0.f;
#pragma unroll
  for (int i = 0; i < 4; ++i) { float d0 = y[i] - mu; vs += d0 * d0; }
#pragma unroll
  for (int d = 1; d < 64; d <<= 1) vs += __shfl_xor(vs, d);
  __syncthreads();
  if (l == 0) red[w] = vs;
  __syncthreads();
  vs = red[0] + red[1] + red[2] + red[3];
  const float rstd = rsqrtf(vs * (1.f / 1024.f) + 1e-5f);
  float* o = out + (size_t)row * 1024;
#pragma unroll
  for (int i = 0; i < 4; ++i) {
    int c = t + i * 256;
    o[c] = (y[i] - mu) * rstd * gamma[c] + beta[c];
  }
}

extern "C" void kernel_launch(void* const* d_in, const int* in_sizes, int n_in,
                              void* d_out, int out_size, void* d_ws, size_t ws_size,
                              hipStream_t stream) {
  const float* x     = (const float*)d_in[0];
  const float* W_q   = (const float*)d_in[1];
  const float* W_k   = (const float*)d_in[2];
  const float* W_v   = (const float*)d_in[3];
  const float* W_o   = (const float*)d_in[4];
  const float* gamma = (const float*)d_in[5];
  const float* beta  = (const float*)d_in[6];
  float* out = (float*)d_out;

  char* ws = (char*)d_ws;
  short* xb   = (short*)ws;  ws += (size_t)8192 * 1024 * 2;
  short* Wb   = (short*)ws;  ws += (size_t)3072 * 1024 * 2;
  short* Wob  = (short*)ws;  ws += (size_t)1024 * 1024 * 2;
  short* qkv  = (short*)ws;  ws += (size_t)8192 * 3072 * 2;
  short* obuf = (short*)ws;  ws += (size_t)8192 * 1024 * 2;
  float* U    = (float*)ws;  ws += (size_t)8192 * 1024 * 4;

  cvt_bf16<<<4096, 256, 0, stream>>>(x, xb, 8192 * 1024);
  cvt_bf16<<<512, 256, 0, stream>>>(W_q, Wb, 1024 * 1024);
  cvt_bf16<<<512, 256, 0, stream>>>(W_k, Wb + 1024 * 1024, 1024 * 1024);
  cvt_bf16<<<512, 256, 0, stream>>>(W_v, Wb + 2 * 1024 * 1024, 1024 * 1024);
  cvt_bf16<<<512, 256, 0, stream>>>(W_o, Wob, 1024 * 1024);

  gemm_bt<1><<<dim3(64, 24), 256, 0, stream>>>(xb, Wb, qkv, 8192, 3072, 1024);
  attn_fwd<<<dim3(32, 64), 256, 0, stream>>>(qkv, obuf);
  gemm_bt<0><<<dim3(64, 8), 256, 0, stream>>>(obuf, Wob, U, 8192, 1024, 1024);
  resid_ln<<<8192, 256, 0, stream>>>(U, x, gamma, beta, out);
}

// Round 2
// 357.900 us; speedup vs baseline: 1.3840x; 1.3840x over previous
//
#include <hip/hip_runtime.h>
#include <stdint.h>

typedef __attribute__((ext_vector_type(8))) short bf16x8;
typedef __attribute__((ext_vector_type(4))) float f32x4;

#define GLOBAL_AS __attribute__((address_space(1)))
#define LDS_AS    __attribute__((address_space(3)))

__device__ __forceinline__ void load_lds16(const void* g, void* l) {
  __builtin_amdgcn_global_load_lds((const GLOBAL_AS void*)g, (LDS_AS void*)l, 16, 0, 0);
}

__device__ __forceinline__ float bf2f(short s) {
  return __uint_as_float(((unsigned)(unsigned short)s) << 16);
}
__device__ __forceinline__ short f2bf(float f) {
  unsigned u = __float_as_uint(f);
  u += 0x7fffu + ((u >> 16) & 1u);
  return (short)(u >> 16);
}

// ---------------- fp32 -> bf16 convert (vectorized) ----------------
__global__ __launch_bounds__(256) void cvt_bf16(const float* __restrict__ in,
                                                short* __restrict__ out, int n) {
  int i = (blockIdx.x * 256 + threadIdx.x) * 8;
  if (i >= n) return;
  float4 a = *(const float4*)(in + i);
  float4 b = *(const float4*)(in + i + 4);
  bf16x8 o;
  o[0] = f2bf(a.x); o[1] = f2bf(a.y); o[2] = f2bf(a.z); o[3] = f2bf(a.w);
  o[4] = f2bf(b.x); o[5] = f2bf(b.y); o[6] = f2bf(b.z); o[7] = f2bf(b.w);
  *(bf16x8*)(out + i) = o;
}

// ---------------- C = A * B^T  (A:[M,K] bf16, B:[N,K] bf16) ----------------
template<int OUT_BF16>
__global__ __launch_bounds__(256) void gemm_bt(const short* __restrict__ A,
                                               const short* __restrict__ B,
                                               void* __restrict__ Cp,
                                               int M, int N, int K) {
  __shared__ short As[128 * 64];
  __shared__ short Bs[128 * 64];
  const int t = threadIdx.x, l = t & 63, w = t >> 6;
  const int g = l >> 4, li = l & 15;
  const int wr = w >> 1, wc = w & 1;
  const int bm = blockIdx.x, bn = blockIdx.y;
  f32x4 acc[4][4] = {};
  const size_t arow0 = (size_t)(bm * 128) * K;
  const size_t brow0 = (size_t)(bn * 128) * K;
  for (int k0 = 0; k0 < K; k0 += 64) {
    __syncthreads();
#pragma unroll
    for (int it = 0; it < 4; ++it) {
      int e = it * 2048 + t * 8;
      int r = e >> 6, c = e & 63;
      load_lds16(A + arow0 + (size_t)r * K + (k0 + c), &As[e]);
      load_lds16(B + brow0 + (size_t)r * K + (k0 + c), &Bs[e]);
    }
    __syncthreads();
#pragma unroll
    for (int kk = 0; kk < 2; ++kk) {
      bf16x8 af[4], bfr[4];
#pragma unroll
      for (int m = 0; m < 4; ++m)
        af[m] = *(const bf16x8*)&As[(wr * 64 + m * 16 + li) * 64 + kk * 32 + g * 8];
#pragma unroll
      for (int n = 0; n < 4; ++n)
        bfr[n] = *(const bf16x8*)&Bs[(wc * 64 + n * 16 + li) * 64 + kk * 32 + g * 8];
#pragma unroll
      for (int m = 0; m < 4; ++m)
#pragma unroll
        for (int n = 0; n < 4; ++n)
          acc[m][n] = __builtin_amdgcn_mfma_f32_16x16x32_bf16(af[m], bfr[n], acc[m][n], 0, 0, 0);
    }
  }
#pragma unroll
  for (int m = 0; m < 4; ++m)
#pragma unroll
    for (int n = 0; n < 4; ++n)
#pragma unroll
      for (int r = 0; r < 4; ++r) {
        int row = bm * 128 + wr * 64 + m * 16 + g * 4 + r;
        int col = bn * 128 + wc * 64 + n * 16 + li;
        if (OUT_BF16)
          ((short*)Cp)[(size_t)row * N + col] = f2bf(acc[m][n][r]);
        else
          ((float*)Cp)[(size_t)row * N + col] = acc[m][n][r];
      }
}

// ---------------- V pre-transpose: qkv V-cols -> VT[bh][d][k] ----------------
__global__ __launch_bounds__(256) void transpose_v(const short* __restrict__ qkv,
                                                   short* __restrict__ VT) {
  const int kt = blockIdx.x;   // 0..31
  const int bh = blockIdx.y;   // 0..63
  const int b = bh >> 4, h = bh & 15;
  __shared__ short T[64][72];
  const int t = threadIdx.x;
  const size_t src = (size_t)b * 2048 * 3072 + 2048 + (size_t)h * 64;
#pragma unroll
  for (int i = 0; i < 2; ++i) {
    int k = i * 32 + (t >> 3);
    int d0 = (t & 7) * 8;
    bf16x8 v = *(const bf16x8*)(qkv + src + (size_t)(kt * 64 + k) * 3072 + d0);
#pragma unroll
    for (int j = 0; j < 8; ++j) T[d0 + j][k] = v[j];
  }
  __syncthreads();
#pragma unroll
  for (int i = 0; i < 2; ++i) {
    int d = i * 32 + (t >> 3);
    int k0 = (t & 7) * 8;
    bf16x8 v = *(const bf16x8*)&T[d][k0];
    *(bf16x8*)(VT + ((size_t)bh * 64 + d) * 2048 + kt * 64 + k0) = v;
  }
}

// ---------------- flash attention ----------------
// qkv: [8192][3072] bf16 (0..1023=Q, 1024..2047=K, 2048..3071=V)
// VT : [64 bh][64 d][2048 k] bf16 (pre-transposed V)
// obuf: [8192][1024] bf16
__global__ __launch_bounds__(256) void attn_fwd(const short* __restrict__ qkv,
                                                const short* __restrict__ VT,
                                                short* __restrict__ obuf) {
  const int qt = blockIdx.x;   // 0..31 : 64-row Q tile
  const int bh = blockIdx.y;   // 0..63
  const int b = bh >> 4, h = bh & 15;
  const int t = threadIdx.x, w = t >> 6, l = t & 63;
  const int g = l >> 4, li = l & 15;

  __shared__ short Ks[64 * 64];      // K tile [key][d], chunk-swizzled
  __shared__ short Vts[64 * 64];     // V^T tile [d][key], chunk-swizzled
  __shared__ short Ps[4][16 * 72];   // per-wave P [q][key], stride 72

  const size_t base = (size_t)b * 2048 * 3072 + (size_t)h * 64;
  const short* Vsrc = VT + (size_t)bh * 64 * 2048;

  // Q fragments, pre-scaled by 1/sqrt(64)=0.125 (exact in bf16)
  const int qrow = qt * 64 + w * 16 + li;
  bf16x8 qf[2];
  {
    const short* qp = qkv + base + (size_t)qrow * 3072;
#pragma unroll
    for (int c = 0; c < 2; ++c) {
      bf16x8 v = *(const bf16x8*)(qp + c * 32 + g * 8);
#pragma unroll
      for (int i = 0; i < 8; ++i) v[i] = f2bf(bf2f(v[i]) * 0.125f);
      qf[c] = v;
    }
  }

  float m_[4], l_[4];
  f32x4 o_[4];
#pragma unroll
  for (int r = 0; r < 4; ++r) { m_[r] = -1e30f; l_[r] = 0.f; }
#pragma unroll
  for (int dj = 0; dj < 4; ++dj) o_[dj] = (f32x4){0.f, 0.f, 0.f, 0.f};

  const int sw = li & 7;   // read-side swizzle key (row & 7)

  for (int kt = 0; kt < 32; ++kt) {
    __syncthreads();   // all waves done reading prev tile's LDS
    // stage K and V^T tiles via swizzled-source global_load_lds
#pragma unroll
    for (int it = 0; it < 2; ++it) {
      int e = it * 2048 + t * 8;      // linear LDS short index
      int r = e >> 6;                 // row (key for K, d for V^T)
      int cs = (e >> 3) & 7;          // LDS chunk slot
      int cg = cs ^ (r & 7);          // global chunk (inverse swizzle)
      load_lds16(qkv + base + 1024 + (size_t)(kt * 64 + r) * 3072 + cg * 8, &Ks[e]);
      load_lds16(Vsrc + (size_t)r * 2048 + kt * 64 + cg * 8, &Vts[e]);
    }
    __syncthreads();

    // S = (Q/8) K^T  -> row q=g*4+r, col key=j*16+li
    f32x4 s_[4];
#pragma unroll
    for (int j = 0; j < 4; ++j) s_[j] = (f32x4){0.f, 0.f, 0.f, 0.f};
#pragma unroll
    for (int c = 0; c < 2; ++c)
#pragma unroll
      for (int j = 0; j < 4; ++j) {
        bf16x8 kf = *(const bf16x8*)&Ks[(j * 16 + li) * 64 + (((c * 4 + g) ^ sw) * 8)];
        s_[j] = __builtin_amdgcn_mfma_f32_16x16x32_bf16(qf[c], kf, s_[j], 0, 0, 0);
      }

    // online softmax per q-row
    float mt[4];
#pragma unroll
    for (int r = 0; r < 4; ++r) {
      float v = s_[0][r];
#pragma unroll
      for (int j = 1; j < 4; ++j) v = fmaxf(v, s_[j][r]);
#pragma unroll
      for (int d = 1; d < 16; d <<= 1) v = fmaxf(v, __shfl_xor(v, d));
      mt[r] = v;
    }
    float al[4], rs[4];
#pragma unroll
    for (int r = 0; r < 4; ++r) {
      float mn = fmaxf(m_[r], mt[r]);
      al[r] = __expf(m_[r] - mn);
      m_[r] = mn;
      rs[r] = 0.f;
    }
#pragma unroll
    for (int j = 0; j < 4; ++j)
#pragma unroll
      for (int r = 0; r < 4; ++r) {
        float p = __expf(s_[j][r] - m_[r]);
        s_[j][r] = p;
        rs[r] += p;
      }
#pragma unroll
    for (int r = 0; r < 4; ++r) {
#pragma unroll
      for (int d = 1; d < 16; d <<= 1) rs[r] += __shfl_xor(rs[r], d);
      l_[r] = l_[r] * al[r] + rs[r];
    }
#pragma unroll
    for (int dj = 0; dj < 4; ++dj)
#pragma unroll
      for (int r = 0; r < 4; ++r) o_[dj][r] *= al[r];

    // P -> per-wave LDS region (wave-private: no block barrier needed)
#pragma unroll
    for (int j = 0; j < 4; ++j)
#pragma unroll
      for (int r = 0; r < 4; ++r)
        Ps[w][(g * 4 + r) * 72 + j * 16 + li] = f2bf(s_[j][r]);
    asm volatile("s_waitcnt lgkmcnt(0)" ::: "memory");

    // O += P V   (A = P [q][k] from Ps, B rows=d from swizzled Vts)
#pragma unroll
    for (int c = 0; c < 2; ++c) {
      bf16x8 pa = *(const bf16x8*)&Ps[w][li * 72 + c * 32 + g * 8];
#pragma unroll
      for (int dj = 0; dj < 4; ++dj) {
        bf16x8 vb = *(const bf16x8*)&Vts[(dj * 16 + li) * 64 + (((c * 4 + g) ^ sw) * 8)];
        o_[dj] = __builtin_amdgcn_mfma_f32_16x16x32_bf16(pa, vb, o_[dj], 0, 0, 0);
      }
    }
  }

  // epilogue: divide by softmax denom, store bf16
#pragma unroll
  for (int r = 0; r < 4; ++r) {
    float inv = 1.f / l_[r];
#pragma unroll
    for (int dj = 0; dj < 4; ++dj) {
      int row = b * 2048 + qt * 64 + w * 16 + g * 4 + r;
      int col = h * 64 + dj * 16 + li;
      obuf[(size_t)row * 1024 + col] = f2bf(o_[dj][r] * inv);
    }
  }
}

// ---------------- residual + LayerNorm (fp32) ----------------
__global__ __launch_bounds__(256) void resid_ln(const float* __restrict__ U,
                                                const float* __restrict__ x,
                                                const float* __restrict__ gamma,
                                                const float* __restrict__ beta,
                                                float* __restrict__ out) {
  const int row = blockIdx.x;
  const int t = threadIdx.x, w = t >> 6, l = t & 63;
  const float* u = U + (size_t)row * 1024;
  const float* xr = x + (size_t)row * 1024;
  float y[4];
  float s = 0.f;
#pragma unroll
  for (int i = 0; i < 4; ++i) {
    int c = t + i * 256;
    y[i] = u[c] + xr[c];
    s += y[i];
  }
#pragma unroll
  for (int d = 1; d < 64; d <<= 1) s += __shfl_xor(s, d);
  __shared__ float red[4];
  if (l == 0) red[w] = s;
  __syncthreads();
  s = red[0] + red[1] + red[2] + red[3];
  const float mu = s * (1.f / 1024.f);
  float vs = 0.f;
#pragma unroll
  for (int i = 0; i < 4; ++i) { float d0 = y[i] - mu; vs += d0 * d0; }
#pragma unroll
  for (int d = 1; d < 64; d <<= 1) vs += __shfl_xor(vs, d);
  __syncthreads();
  if (l == 0) red[w] = vs;
  __syncthreads();
  vs = red[0] + red[1] + red[2] + red[3];
  const float rstd = rsqrtf(vs * (1.f / 1024.f) + 1e-5f);
  float* o = out + (size_t)row * 1024;
#pragma unroll
  for (int i = 0; i < 4; ++i) {
    int c = t + i * 256;
    o[c] = (y[i] - mu) * rstd * gamma[c] + beta[c];
  }
}

extern "C" void kernel_launch(void* const* d_in, const int* in_sizes, int n_in,
                              void* d_out, int out_size, void* d_ws, size_t ws_size,
                              hipStream_t stream) {
  const float* x     = (const float*)d_in[0];
  const float* W_q   = (const float*)d_in[1];
  const float* W_k   = (const float*)d_in[2];
  const float* W_v   = (const float*)d_in[3];
  const float* W_o   = (const float*)d_in[4];
  const float* gamma = (const float*)d_in[5];
  const float* beta  = (const float*)d_in[6];
  float* out = (float*)d_out;

  char* ws = (char*)d_ws;
  short* xb   = (short*)ws;  ws += (size_t)8192 * 1024 * 2;
  short* Wb   = (short*)ws;  ws += (size_t)3072 * 1024 * 2;
  short* Wob  = (short*)ws;  ws += (size_t)1024 * 1024 * 2;
  short* qkv  = (short*)ws;  ws += (size_t)8192 * 3072 * 2;
  short* obuf = (short*)ws;  ws += (size_t)8192 * 1024 * 2;
  float* U    = (float*)ws;  ws += (size_t)8192 * 1024 * 4;
  short* VT   = (short*)U;   // aliased: VT dead before U is written

  cvt_bf16<<<4096, 256, 0, stream>>>(x, xb, 8192 * 1024);
  cvt_bf16<<<512, 256, 0, stream>>>(W_q, Wb, 1024 * 1024);
  cvt_bf16<<<512, 256, 0, stream>>>(W_k, Wb + 1024 * 1024, 1024 * 1024);
  cvt_bf16<<<512, 256, 0, stream>>>(W_v, Wb + 2 * 1024 * 1024, 1024 * 1024);
  cvt_bf16<<<512, 256, 0, stream>>>(W_o, Wob, 1024 * 1024);

  gemm_bt<1><<<dim3(64, 24), 256, 0, stream>>>(xb, Wb, qkv, 8192, 3072, 1024);
  transpose_v<<<dim3(32, 64), 256, 0, stream>>>(qkv, VT);
  attn_fwd<<<dim3(32, 64), 256, 0, stream>>>(qkv, VT, obuf);
  gemm_bt<0><<<dim3(64, 8), 256, 0, stream>>>(obuf, Wob, U, 8192, 1024, 1024);
  resid_ln<<<8192, 256, 0, stream>>>(U, x, gamma, beta, out);
}

// Round 3
// 305.319 us; speedup vs baseline: 1.6223x; 1.1722x over previous
//
#include <hip/hip_runtime.h>
#include <hip/hip_bf16.h>
#include <stdint.h>

typedef __attribute__((ext_vector_type(8))) short bf16x8;
typedef __attribute__((ext_vector_type(4))) float f32x4;

#define GLOBAL_AS __attribute__((address_space(1)))
#define LDS_AS    __attribute__((address_space(3)))

__device__ __forceinline__ void load_lds16(const void* g, void* l) {
  __builtin_amdgcn_global_load_lds((const GLOBAL_AS void*)g, (LDS_AS void*)l, 16, 0, 0);
}

__device__ __forceinline__ float bf2f(short s) {
  return __uint_as_float(((unsigned)(unsigned short)s) << 16);
}
// native HW convert (RTNE), 1 inst — manual bit-trick costs 4 VALU
__device__ __forceinline__ short f2bfn(float f) {
  __hip_bfloat16 h = __float2bfloat16(f);
  return __builtin_bit_cast(short, h);
}

// ---------------- fp32 -> bf16 convert (vectorized) ----------------
__global__ __launch_bounds__(256) void cvt_bf16(const float* __restrict__ in,
                                                short* __restrict__ out, int n) {
  int i = (blockIdx.x * 256 + threadIdx.x) * 8;
  if (i >= n) return;
  float4 a = *(const float4*)(in + i);
  float4 b = *(const float4*)(in + i + 4);
  bf16x8 o;
  o[0] = f2bfn(a.x); o[1] = f2bfn(a.y); o[2] = f2bfn(a.z); o[3] = f2bfn(a.w);
  o[4] = f2bfn(b.x); o[5] = f2bfn(b.y); o[6] = f2bfn(b.z); o[7] = f2bfn(b.w);
  *(bf16x8*)(out + i) = o;
}

// ---------------- C = A * B^T  (A:[M,K] bf16, B:[N,K] bf16) ----------------
template<int OUT_BF16>
__global__ __launch_bounds__(256) void gemm_bt(const short* __restrict__ A,
                                               const short* __restrict__ B,
                                               void* __restrict__ Cp,
                                               int M, int N, int K) {
  __shared__ short As[128 * 64];
  __shared__ short Bs[128 * 64];
  const int t = threadIdx.x, l = t & 63, w = t >> 6;
  const int g = l >> 4, li = l & 15;
  const int wr = w >> 1, wc = w & 1;
  const int bm = blockIdx.x, bn = blockIdx.y;
  f32x4 acc[4][4] = {};
  const size_t arow0 = (size_t)(bm * 128) * K;
  const size_t brow0 = (size_t)(bn * 128) * K;
  for (int k0 = 0; k0 < K; k0 += 64) {
    __syncthreads();
#pragma unroll
    for (int it = 0; it < 4; ++it) {
      int e = it * 2048 + t * 8;
      int r = e >> 6, c = e & 63;
      load_lds16(A + arow0 + (size_t)r * K + (k0 + c), &As[e]);
      load_lds16(B + brow0 + (size_t)r * K + (k0 + c), &Bs[e]);
    }
    __syncthreads();
#pragma unroll
    for (int kk = 0; kk < 2; ++kk) {
      bf16x8 af[4], bfr[4];
#pragma unroll
      for (int m = 0; m < 4; ++m)
        af[m] = *(const bf16x8*)&As[(wr * 64 + m * 16 + li) * 64 + kk * 32 + g * 8];
#pragma unroll
      for (int n = 0; n < 4; ++n)
        bfr[n] = *(const bf16x8*)&Bs[(wc * 64 + n * 16 + li) * 64 + kk * 32 + g * 8];
#pragma unroll
      for (int m = 0; m < 4; ++m)
#pragma unroll
        for (int n = 0; n < 4; ++n)
          acc[m][n] = __builtin_amdgcn_mfma_f32_16x16x32_bf16(af[m], bfr[n], acc[m][n], 0, 0, 0);
    }
  }
#pragma unroll
  for (int m = 0; m < 4; ++m)
#pragma unroll
    for (int n = 0; n < 4; ++n)
#pragma unroll
      for (int r = 0; r < 4; ++r) {
        int row = bm * 128 + wr * 64 + m * 16 + g * 4 + r;
        int col = bn * 128 + wc * 64 + n * 16 + li;
        if (OUT_BF16)
          ((short*)Cp)[(size_t)row * N + col] = f2bfn(acc[m][n][r]);
        else
          ((float*)Cp)[(size_t)row * N + col] = acc[m][n][r];
      }
}

// ---------------- V pre-transpose: qkv V-cols -> VT[bh][d][k] ----------------
__global__ __launch_bounds__(256) void transpose_v(const short* __restrict__ qkv,
                                                   short* __restrict__ VT) {
  const int kt = blockIdx.x;   // 0..31
  const int bh = blockIdx.y;   // 0..63
  const int b = bh >> 4, h = bh & 15;
  __shared__ short T[64][72];
  const int t = threadIdx.x;
  const size_t src = (size_t)b * 2048 * 3072 + 2048 + (size_t)h * 64;
#pragma unroll
  for (int i = 0; i < 2; ++i) {
    int k = i * 32 + (t >> 3);
    int d0 = (t & 7) * 8;
    bf16x8 v = *(const bf16x8*)(qkv + src + (size_t)(kt * 64 + k) * 3072 + d0);
#pragma unroll
    for (int j = 0; j < 8; ++j) T[d0 + j][k] = v[j];
  }
  __syncthreads();
#pragma unroll
  for (int i = 0; i < 2; ++i) {
    int d = i * 32 + (t >> 3);
    int k0 = (t & 7) * 8;
    bf16x8 v = *(const bf16x8*)&T[d][k0];
    *(bf16x8*)(VT + ((size_t)bh * 64 + d) * 2048 + kt * 64 + k0) = v;
  }
}

// ---------------- flash attention ----------------
// qkv: [8192][3072] bf16 (0..1023=Q, 1024..2047=K, 2048..3071=V)
// VT : [64 bh][64 d][2048 k] bf16 (pre-transposed V)
// obuf: [8192][1024] bf16
__global__ __launch_bounds__(256) void attn_fwd(const short* __restrict__ qkv,
                                                const short* __restrict__ VT,
                                                short* __restrict__ obuf) {
  // XCD-aware swizzle: 2048 blocks, each XCD owns 256 consecutive works
  // (= 8 heads x 32 q-tiles) so K/V stay L2-resident per XCD.
  const int f0 = blockIdx.x;
  const int work = (f0 & 7) * 256 + (f0 >> 3);
  const int qt = work & 31;    // 0..31 : 64-row Q tile
  const int bh = work >> 5;    // 0..63
  const int b = bh >> 4, h = bh & 15;
  const int t = threadIdx.x, w = t >> 6, l = t & 63;
  const int g = l >> 4, li = l & 15;

  __shared__ short Ks[2][64 * 64];   // K tile [key][d], chunk-swizzled, dbuf
  __shared__ short Vts[2][64 * 64];  // V^T tile [d][key], chunk-swizzled, dbuf
  __shared__ short Ps[4][16 * 72];   // per-wave P [q][key], stride 72

  const size_t base = (size_t)b * 2048 * 3072 + (size_t)h * 64;
  const short* Vsrc = VT + (size_t)bh * 64 * 2048;

  // Q fragments, pre-scaled by 0.125*log2(e)  (exp2 domain)
  const int qrow = qt * 64 + w * 16 + li;
  bf16x8 qf[2];
  {
    const float QSC = 0.125f * 1.44269504088896341f;
    const short* qp = qkv + base + (size_t)qrow * 3072;
#pragma unroll
    for (int c = 0; c < 2; ++c) {
      bf16x8 v = *(const bf16x8*)(qp + c * 32 + g * 8);
#pragma unroll
      for (int i = 0; i < 8; ++i) v[i] = f2bfn(bf2f(v[i]) * QSC);
      qf[c] = v;
    }
  }

  // softmax stats live at q = li (one q-row per lane, replicated over g)
  float m_ = -1e30f, l_ = 0.f;
  f32x4 o_[4];
#pragma unroll
  for (int dj = 0; dj < 4; ++dj) o_[dj] = (f32x4){0.f, 0.f, 0.f, 0.f};

  const int sw = li & 7;   // read-side swizzle key (row & 7)

#define STAGE(buf, kt_)                                                          \
  {                                                                              \
    _Pragma("unroll")                                                            \
    for (int it = 0; it < 2; ++it) {                                             \
      int e = it * 2048 + t * 8;                                                 \
      int r = e >> 6;                                                            \
      int cs = (e >> 3) & 7;                                                     \
      int cg = cs ^ (r & 7);                                                     \
      load_lds16(qkv + base + 1024 + (size_t)((kt_) * 64 + r) * 3072 + cg * 8,   \
                 &Ks[buf][e]);                                                   \
      load_lds16(Vsrc + (size_t)r * 2048 + (kt_) * 64 + cg * 8, &Vts[buf][e]);   \
    }                                                                            \
  }

  STAGE(0, 0);
  asm volatile("s_waitcnt vmcnt(0)" ::: "memory");
  __syncthreads();

  for (int kt = 0; kt < 32; ++kt) {
    const int cur = kt & 1;
    if (kt + 1 < 32) STAGE(cur ^ 1, kt + 1);   // prefetch overlaps compute

    // S^T = K (Q scaled)^T : tile j -> key = j*16+g*4+r, q = li
    f32x4 s_[4];
#pragma unroll
    for (int j = 0; j < 4; ++j) s_[j] = (f32x4){0.f, 0.f, 0.f, 0.f};
#pragma unroll
    for (int c = 0; c < 2; ++c)
#pragma unroll
      for (int j = 0; j < 4; ++j) {
        bf16x8 kf = *(const bf16x8*)&Ks[cur][(j * 16 + li) * 64 + (((c * 4 + g) ^ sw) * 8)];
        s_[j] = __builtin_amdgcn_mfma_f32_16x16x32_bf16(kf, qf[c], s_[j], 0, 0, 0);
      }

    // tile max over keys for q=li: 15 in-lane + 2 shuffles
    float mt = fmaxf(fmaxf(s_[0][0], s_[0][1]), fmaxf(s_[0][2], s_[0][3]));
#pragma unroll
    for (int j = 1; j < 4; ++j)
      mt = fmaxf(mt, fmaxf(fmaxf(s_[j][0], s_[j][1]), fmaxf(s_[j][2], s_[j][3])));
    mt = fmaxf(mt, __shfl_xor(mt, 16));
    mt = fmaxf(mt, __shfl_xor(mt, 32));

    // defer-max: only rescale when max grew by > 8 (log2 domain)
    if (!__all(mt <= m_ + 8.f)) {
      float mn = fmaxf(m_, mt);
      float al = exp2f(m_ - mn);
      m_ = mn;
      l_ *= al;
#pragma unroll
      for (int r = 0; r < 4; ++r) {
        float alr = __shfl(al, (l & 48) | (g * 4 + r));  // stats for q=g*4+r
#pragma unroll
        for (int dj = 0; dj < 4; ++dj) o_[dj][r] *= alr;
      }
    }

    // P = exp2(S - m), row-sum, pack to bf16, one b64 LDS write per j
    float rs = 0.f;
#pragma unroll
    for (int j = 0; j < 4; ++j) {
      float p0 = exp2f(s_[j][0] - m_);
      float p1 = exp2f(s_[j][1] - m_);
      float p2 = exp2f(s_[j][2] - m_);
      float p3 = exp2f(s_[j][3] - m_);
      rs += (p0 + p1) + (p2 + p3);
      short4 pk;
      pk.x = f2bfn(p0); pk.y = f2bfn(p1); pk.z = f2bfn(p2); pk.w = f2bfn(p3);
      *(short4*)&Ps[w][li * 72 + j * 16 + g * 4] = pk;
    }
    rs += __shfl_xor(rs, 16);
    rs += __shfl_xor(rs, 32);
    l_ += rs;

    // O += P V   (A = P[q][k] from Ps, B rows=d from swizzled Vts)
#pragma unroll
    for (int c = 0; c < 2; ++c) {
      bf16x8 pa = *(const bf16x8*)&Ps[w][li * 72 + c * 32 + g * 8];
#pragma unroll
      for (int dj = 0; dj < 4; ++dj) {
        bf16x8 vb = *(const bf16x8*)&Vts[cur][(dj * 16 + li) * 64 + (((c * 4 + g) ^ sw) * 8)];
        o_[dj] = __builtin_amdgcn_mfma_f32_16x16x32_bf16(pa, vb, o_[dj], 0, 0, 0);
      }
    }

    asm volatile("s_waitcnt vmcnt(0)" ::: "memory");  // next tile staged
    __syncthreads();
  }

  // epilogue: divide by softmax denom (broadcast per O-row), store bf16
  const float il = 1.f / l_;
#pragma unroll
  for (int r = 0; r < 4; ++r) {
    float ilr = __shfl(il, (l & 48) | (g * 4 + r));
    int row = b * 2048 + qt * 64 + w * 16 + g * 4 + r;
#pragma unroll
    for (int dj = 0; dj < 4; ++dj) {
      int col = h * 64 + dj * 16 + li;
      obuf[(size_t)row * 1024 + col] = f2bfn(o_[dj][r] * ilr);
    }
  }
#undef STAGE
}

// ---------------- residual + LayerNorm (fp32) ----------------
__global__ __launch_bounds__(256) void resid_ln(const float* __restrict__ U,
                                                const float* __restrict__ x,
                                                const float* __restrict__ gamma,
                                                const float* __restrict__ beta,
                                                float* __restrict__ out) {
  const int row = blockIdx.x;
  const int t = threadIdx.x, w = t >> 6, l = t & 63;
  const float* u = U + (size_t)row * 1024;
  const float* xr = x + (size_t)row * 1024;
  float y[4];
  float s = 0.f;
#pragma unroll
  for (int i = 0; i < 4; ++i) {
    int c = t + i * 256;
    y[i] = u[c] + xr[c];
    s += y[i];
  }
#pragma unroll
  for (int d = 1; d < 64; d <<= 1) s += __shfl_xor(s, d);
  __shared__ float red[4];
  if (l == 0) red[w] = s;
  __syncthreads();
  s = red[0] + red[1] + red[2] + red[3];
  const float mu = s * (1.f / 1024.f);
  float vs = 0.f;
#pragma unroll
  for (int i = 0; i < 4; ++i) { float d0 = y[i] - mu; vs += d0 * d0; }
#pragma unroll
  for (int d = 1; d < 64; d <<= 1) vs += __shfl_xor(vs, d);
  __syncthreads();
  if (l == 0) red[w] = vs;
  __syncthreads();
  vs = red[0] + red[1] + red[2] + red[3];
  const float rstd = rsqrtf(vs * (1.f / 1024.f) + 1e-5f);
  float* o = out + (size_t)row * 1024;
#pragma unroll
  for (int i = 0; i < 4; ++i) {
    int c = t + i * 256;
    o[c] = (y[i] - mu) * rstd * gamma[c] + beta[c];
  }
}

extern "C" void kernel_launch(void* const* d_in, const int* in_sizes, int n_in,
                              void* d_out, int out_size, void* d_ws, size_t ws_size,
                              hipStream_t stream) {
  const float* x     = (const float*)d_in[0];
  const float* W_q   = (const float*)d_in[1];
  const float* W_k   = (const float*)d_in[2];
  const float* W_v   = (const float*)d_in[3];
  const float* W_o   = (const float*)d_in[4];
  const float* gamma = (const float*)d_in[5];
  const float* beta  = (const float*)d_in[6];
  float* out = (float*)d_out;

  char* ws = (char*)d_ws;
  short* xb   = (short*)ws;  ws += (size_t)8192 * 1024 * 2;
  short* Wb   = (short*)ws;  ws += (size_t)3072 * 1024 * 2;
  short* Wob  = (short*)ws;  ws += (size_t)1024 * 1024 * 2;
  short* qkv  = (short*)ws;  ws += (size_t)8192 * 3072 * 2;
  short* obuf = (short*)ws;  ws += (size_t)8192 * 1024 * 2;
  float* U    = (float*)ws;  ws += (size_t)8192 * 1024 * 4;
  short* VT   = (short*)U;   // aliased: VT dead before U is written

  cvt_bf16<<<4096, 256, 0, stream>>>(x, xb, 8192 * 1024);
  cvt_bf16<<<512, 256, 0, stream>>>(W_q, Wb, 1024 * 1024);
  cvt_bf16<<<512, 256, 0, stream>>>(W_k, Wb + 1024 * 1024, 1024 * 1024);
  cvt_bf16<<<512, 256, 0, stream>>>(W_v, Wb + 2 * 1024 * 1024, 1024 * 1024);
  cvt_bf16<<<512, 256, 0, stream>>>(W_o, Wob, 1024 * 1024);

  gemm_bt<1><<<dim3(64, 24), 256, 0, stream>>>(xb, Wb, qkv, 8192, 3072, 1024);
  transpose_v<<<dim3(32, 64), 256, 0, stream>>>(qkv, VT);
  attn_fwd<<<2048, 256, 0, stream>>>(qkv, VT, obuf);
  gemm_bt<0><<<dim3(64, 8), 256, 0, stream>>>(obuf, Wob, U, 8192, 1024, 1024);
  resid_ln<<<8192, 256, 0, stream>>>(U, x, gamma, beta, out);
}

// Round 4
// 293.173 us; speedup vs baseline: 1.6895x; 1.0414x over previous
//
#include <hip/hip_runtime.h>
#include <hip/hip_bf16.h>
#include <stdint.h>

typedef __attribute__((ext_vector_type(8))) short bf16x8;
typedef __attribute__((ext_vector_type(4))) float f32x4;

#define GLOBAL_AS __attribute__((address_space(1)))
#define LDS_AS    __attribute__((address_space(3)))

__device__ __forceinline__ void load_lds16(const void* g, void* l) {
  __builtin_amdgcn_global_load_lds((const GLOBAL_AS void*)g, (LDS_AS void*)l, 16, 0, 0);
}

__device__ __forceinline__ float bf2f(short s) {
  return __uint_as_float(((unsigned)(unsigned short)s) << 16);
}
__device__ __forceinline__ short f2bfn(float f) {
  __hip_bfloat16 h = __float2bfloat16(f);
  return __builtin_bit_cast(short, h);
}

// ---------------- fp32 -> bf16 convert: activations ----------------
__global__ __launch_bounds__(256) void cvt_bf16(const float* __restrict__ in,
                                                short* __restrict__ out, int n) {
  int i = (blockIdx.x * 256 + threadIdx.x) * 8;
  if (i >= n) return;
  float4 a = *(const float4*)(in + i);
  float4 b = *(const float4*)(in + i + 4);
  bf16x8 o;
  o[0] = f2bfn(a.x); o[1] = f2bfn(a.y); o[2] = f2bfn(a.z); o[3] = f2bfn(a.w);
  o[4] = f2bfn(b.x); o[5] = f2bfn(b.y); o[6] = f2bfn(b.z); o[7] = f2bfn(b.w);
  *(bf16x8*)(out + i) = o;
}

// ---------------- fp32 -> bf16: all four weight matrices in one launch ------
__global__ __launch_bounds__(256) void cvt_w(const float* __restrict__ q,
                                             const float* __restrict__ k,
                                             const float* __restrict__ v,
                                             const float* __restrict__ o,
                                             short* __restrict__ Wb,
                                             short* __restrict__ Wob) {
  const int sel = blockIdx.x >> 9;          // 0..3
  const int inner = blockIdx.x & 511;
  const int i = (inner * 256 + threadIdx.x) * 8;
  const float* src = sel == 0 ? q : sel == 1 ? k : sel == 2 ? v : o;
  short* dst = sel == 0 ? Wb : sel == 1 ? Wb + 1024 * 1024
             : sel == 2 ? Wb + 2 * 1024 * 1024 : Wob;
  float4 a = *(const float4*)(src + i);
  float4 b = *(const float4*)(src + i + 4);
  bf16x8 ov;
  ov[0] = f2bfn(a.x); ov[1] = f2bfn(a.y); ov[2] = f2bfn(a.z); ov[3] = f2bfn(a.w);
  ov[4] = f2bfn(b.x); ov[5] = f2bfn(b.y); ov[6] = f2bfn(b.z); ov[7] = f2bfn(b.w);
  *(bf16x8*)(dst + i) = ov;
}

// ---------------- C = A * B^T  (A:[M=8192,K] bf16, B:[N,K] bf16) ------------
// grid = 64*NBN (1-D), XCD-swizzled: each XCD owns 8 bm-tiles (2MB A-chunk).
template<int OUT_BF16>
__global__ __launch_bounds__(256) void gemm_bt(const short* __restrict__ A,
                                               const short* __restrict__ B,
                                               void* __restrict__ Cp,
                                               int M, int N, int K) {
  __shared__ short As[128 * 64];
  __shared__ short Bs[128 * 64];
  const int t = threadIdx.x, l = t & 63, w = t >> 6;
  const int g = l >> 4, li = l & 15;
  const int wr = w >> 1, wc = w & 1;
  const int bid = blockIdx.x;
  const int bm = (bid & 7) * 8 + ((bid >> 3) & 7);
  const int bn = bid >> 6;
  f32x4 acc[4][4] = {};
  const size_t arow0 = (size_t)(bm * 128) * K;
  const size_t brow0 = (size_t)(bn * 128) * K;
  for (int k0 = 0; k0 < K; k0 += 64) {
    __syncthreads();
#pragma unroll
    for (int it = 0; it < 4; ++it) {
      int e = it * 2048 + t * 8;
      int r = e >> 6, c = e & 63;
      load_lds16(A + arow0 + (size_t)r * K + (k0 + c), &As[e]);
      load_lds16(B + brow0 + (size_t)r * K + (k0 + c), &Bs[e]);
    }
    __syncthreads();
#pragma unroll
    for (int kk = 0; kk < 2; ++kk) {
      bf16x8 af[4], bfr[4];
#pragma unroll
      for (int m = 0; m < 4; ++m)
        af[m] = *(const bf16x8*)&As[(wr * 64 + m * 16 + li) * 64 + kk * 32 + g * 8];
#pragma unroll
      for (int n = 0; n < 4; ++n)
        bfr[n] = *(const bf16x8*)&Bs[(wc * 64 + n * 16 + li) * 64 + kk * 32 + g * 8];
#pragma unroll
      for (int m = 0; m < 4; ++m)
#pragma unroll
        for (int n = 0; n < 4; ++n)
          acc[m][n] = __builtin_amdgcn_mfma_f32_16x16x32_bf16(af[m], bfr[n], acc[m][n], 0, 0, 0);
    }
  }
#pragma unroll
  for (int m = 0; m < 4; ++m)
#pragma unroll
    for (int n = 0; n < 4; ++n)
#pragma unroll
      for (int r = 0; r < 4; ++r) {
        int row = bm * 128 + wr * 64 + m * 16 + g * 4 + r;
        int col = bn * 128 + wc * 64 + n * 16 + li;
        if (OUT_BF16)
          ((short*)Cp)[(size_t)row * N + col] = f2bfn(acc[m][n][r]);
        else
          ((float*)Cp)[(size_t)row * N + col] = acc[m][n][r];
      }
}

// ---------------- V pre-transpose: qkv V-cols -> VT[bh][d][k] ----------------
__global__ __launch_bounds__(256) void transpose_v(const short* __restrict__ qkv,
                                                   short* __restrict__ VT) {
  const int kt = blockIdx.x;   // 0..31
  const int bh = blockIdx.y;   // 0..63
  const int b = bh >> 4, h = bh & 15;
  __shared__ short T[64][72];
  const int t = threadIdx.x;
  const size_t src = (size_t)b * 2048 * 3072 + 2048 + (size_t)h * 64;
#pragma unroll
  for (int i = 0; i < 2; ++i) {
    int k = i * 32 + (t >> 3);
    int d0 = (t & 7) * 8;
    bf16x8 v = *(const bf16x8*)(qkv + src + (size_t)(kt * 64 + k) * 3072 + d0);
#pragma unroll
    for (int j = 0; j < 8; ++j) T[d0 + j][k] = v[j];
  }
  __syncthreads();
#pragma unroll
  for (int i = 0; i < 2; ++i) {
    int d = i * 32 + (t >> 3);
    int k0 = (t & 7) * 8;
    bf16x8 v = *(const bf16x8*)&T[d][k0];
    *(bf16x8*)(VT + ((size_t)bh * 64 + d) * 2048 + kt * 64 + k0) = v;
  }
}

// ---------------- flash attention ----------------
__global__ __launch_bounds__(256) void attn_fwd(const short* __restrict__ qkv,
                                                const short* __restrict__ VT,
                                                short* __restrict__ obuf) {
  const int f0 = blockIdx.x;
  const int work = (f0 & 7) * 256 + (f0 >> 3);
  const int qt = work & 31;
  const int bh = work >> 5;
  const int b = bh >> 4, h = bh & 15;
  const int t = threadIdx.x, w = t >> 6, l = t & 63;
  const int g = l >> 4, li = l & 15;

  __shared__ short Ks[2][64 * 64];
  __shared__ short Vts[2][64 * 64];
  __shared__ short Ps[4][16 * 72];

  const size_t base = (size_t)b * 2048 * 3072 + (size_t)h * 64;
  const short* Vsrc = VT + (size_t)bh * 64 * 2048;

  const int qrow = qt * 64 + w * 16 + li;
  bf16x8 qf[2];
  {
    const float QSC = 0.125f * 1.44269504088896341f;  // exp2 domain
    const short* qp = qkv + base + (size_t)qrow * 3072;
#pragma unroll
    for (int c = 0; c < 2; ++c) {
      bf16x8 v = *(const bf16x8*)(qp + c * 32 + g * 8);
#pragma unroll
      for (int i = 0; i < 8; ++i) v[i] = f2bfn(bf2f(v[i]) * QSC);
      qf[c] = v;
    }
  }

  bf16x8 ones;
#pragma unroll
  for (int i = 0; i < 8; ++i) ones[i] = (short)0x3F80;  // bf16 1.0

  float m_ = -1e30f;
  f32x4 o_[4], lacc;
#pragma unroll
  for (int dj = 0; dj < 4; ++dj) o_[dj] = (f32x4){0.f, 0.f, 0.f, 0.f};
  lacc = (f32x4){0.f, 0.f, 0.f, 0.f};

  const int sw = li & 7;

#define STAGE(buf, kt_)                                                          \
  {                                                                              \
    _Pragma("unroll")                                                            \
    for (int it = 0; it < 2; ++it) {                                             \
      int e = it * 2048 + t * 8;                                                 \
      int r = e >> 6;                                                            \
      int cs = (e >> 3) & 7;                                                     \
      int cg = cs ^ (r & 7);                                                     \
      load_lds16(qkv + base + 1024 + (size_t)((kt_) * 64 + r) * 3072 + cg * 8,   \
                 &Ks[buf][e]);                                                   \
      load_lds16(Vsrc + (size_t)r * 2048 + (kt_) * 64 + cg * 8, &Vts[buf][e]);   \
    }                                                                            \
  }

  STAGE(0, 0);
  asm volatile("s_waitcnt vmcnt(0)" ::: "memory");
  __syncthreads();

  for (int kt = 0; kt < 32; ++kt) {
    const int cur = kt & 1;
    if (kt + 1 < 32) STAGE(cur ^ 1, kt + 1);

    // S^T = K (Q scaled)^T : tile j -> key = j*16+g*4+r, q = li
    f32x4 s_[4];
#pragma unroll
    for (int j = 0; j < 4; ++j) s_[j] = (f32x4){0.f, 0.f, 0.f, 0.f};
#pragma unroll
    for (int c = 0; c < 2; ++c)
#pragma unroll
      for (int j = 0; j < 4; ++j) {
        bf16x8 kf = *(const bf16x8*)&Ks[cur][(j * 16 + li) * 64 + (((c * 4 + g) ^ sw) * 8)];
        s_[j] = __builtin_amdgcn_mfma_f32_16x16x32_bf16(kf, qf[c], s_[j], 0, 0, 0);
      }

    // tile max (v_max3-friendly tree), then 2 cross-g shuffles
    float mt = fmaxf(fmaxf(s_[0][0], s_[0][1]), s_[0][2]);
    mt = fmaxf(fmaxf(mt, s_[0][3]), s_[1][0]);
    mt = fmaxf(fmaxf(mt, s_[1][1]), s_[1][2]);
    mt = fmaxf(fmaxf(mt, s_[1][3]), s_[2][0]);
    mt = fmaxf(fmaxf(mt, s_[2][1]), s_[2][2]);
    mt = fmaxf(fmaxf(mt, s_[2][3]), s_[3][0]);
    mt = fmaxf(fmaxf(mt, s_[3][1]), s_[3][2]);
    mt = fmaxf(mt, s_[3][3]);
    mt = fmaxf(mt, __shfl_xor(mt, 16));
    mt = fmaxf(mt, __shfl_xor(mt, 32));

    // defer-max (log2 domain, THR=8): rescale O and l-acc together
    if (!__all(mt <= m_ + 8.f)) {
      float mn = fmaxf(m_, mt);
      float al = exp2f(m_ - mn);
      m_ = mn;
#pragma unroll
      for (int r = 0; r < 4; ++r) {
        float alr = __shfl(al, (l & 48) | (g * 4 + r));
#pragma unroll
        for (int dj = 0; dj < 4; ++dj) o_[dj][r] *= alr;
        lacc[r] *= alr;
      }
    }

    // P = exp2(S - m), pack via v_cvt_pk, one b64 write per j
#pragma unroll
    for (int j = 0; j < 4; ++j) {
      float p0 = exp2f(s_[j][0] - m_);
      float p1 = exp2f(s_[j][1] - m_);
      float p2 = exp2f(s_[j][2] - m_);
      float p3 = exp2f(s_[j][3] - m_);
      unsigned u0, u1;
      asm("v_cvt_pk_bf16_f32 %0, %1, %2" : "=v"(u0) : "v"(p0), "v"(p1));
      asm("v_cvt_pk_bf16_f32 %0, %1, %2" : "=v"(u1) : "v"(p2), "v"(p3));
      uint2 pk2; pk2.x = u0; pk2.y = u1;
      *(uint2*)&Ps[w][li * 72 + j * 16 + g * 4] = pk2;
    }
    asm volatile("s_waitcnt lgkmcnt(0)" ::: "memory");

    // O += P V ; l += P * ones (2 extra MFMA replace the VALU row-sum)
#pragma unroll
    for (int c = 0; c < 2; ++c) {
      bf16x8 pa = *(const bf16x8*)&Ps[w][li * 72 + c * 32 + g * 8];
      lacc = __builtin_amdgcn_mfma_f32_16x16x32_bf16(pa, ones, lacc, 0, 0, 0);
#pragma unroll
      for (int dj = 0; dj < 4; ++dj) {
        bf16x8 vb = *(const bf16x8*)&Vts[cur][(dj * 16 + li) * 64 + (((c * 4 + g) ^ sw) * 8)];
        o_[dj] = __builtin_amdgcn_mfma_f32_16x16x32_bf16(pa, vb, o_[dj], 0, 0, 0);
      }
    }

    asm volatile("s_waitcnt vmcnt(0)" ::: "memory");
    __syncthreads();
  }

  // epilogue: lacc is already in O row layout -> no shuffles
#pragma unroll
  for (int r = 0; r < 4; ++r) {
    float ilr = 1.f / lacc[r];
    int row = b * 2048 + qt * 64 + w * 16 + g * 4 + r;
#pragma unroll
    for (int dj = 0; dj < 4; ++dj) {
      int col = h * 64 + dj * 16 + li;
      obuf[(size_t)row * 1024 + col] = f2bfn(o_[dj][r] * ilr);
    }
  }
#undef STAGE
}

// ---------------- residual + LayerNorm (fp32, float4) ----------------
__global__ __launch_bounds__(256) void resid_ln(const float* __restrict__ U,
                                                const float* __restrict__ x,
                                                const float* __restrict__ gamma,
                                                const float* __restrict__ beta,
                                                float* __restrict__ out) {
  const int row = blockIdx.x;
  const int t = threadIdx.x, w = t >> 6, l = t & 63;
  const float4 uu = *(const float4*)(U + (size_t)row * 1024 + t * 4);
  const float4 xx = *(const float4*)(x + (size_t)row * 1024 + t * 4);
  float y[4] = {uu.x + xx.x, uu.y + xx.y, uu.z + xx.z, uu.w + xx.w};
  float s = (y[0] + y[1]) + (y[2] + y[3]);
#pragma unroll
  for (int d = 1; d < 64; d <<= 1) s += __shfl_xor(s, d);
  __shared__ float red[4];
  if (l == 0) red[w] = s;
  __syncthreads();
  s = red[0] + red[1] + red[2] + red[3];
  const float mu = s * (1.f / 1024.f);
  float vs = 0.f;
#pragma unroll
  for (int i = 0; i < 4; ++i) { float d0 = y[i] - mu; vs += d0 * d0; }
#pragma unroll
  for (int d = 1; d < 64; d <<= 1) vs += __shfl_xor(vs, d);
  __syncthreads();
  if (l == 0) red[w] = vs;
  __syncthreads();
  vs = red[0] + red[1] + red[2] + red[3];
  const float rstd = rsqrtf(vs * (1.f / 1024.f) + 1e-5f);
  const float4 gg = *(const float4*)(gamma + t * 4);
  const float4 bb = *(const float4*)(beta + t * 4);
  float4 oo;
  oo.x = (y[0] - mu) * rstd * gg.x + bb.x;
  oo.y = (y[1] - mu) * rstd * gg.y + bb.y;
  oo.z = (y[2] - mu) * rstd * gg.z + bb.z;
  oo.w = (y[3] - mu) * rstd * gg.w + bb.w;
  *(float4*)(out + (size_t)row * 1024 + t * 4) = oo;
}

extern "C" void kernel_launch(void* const* d_in, const int* in_sizes, int n_in,
                              void* d_out, int out_size, void* d_ws, size_t ws_size,
                              hipStream_t stream) {
  const float* x     = (const float*)d_in[0];
  const float* W_q   = (const float*)d_in[1];
  const float* W_k   = (const float*)d_in[2];
  const float* W_v   = (const float*)d_in[3];
  const float* W_o   = (const float*)d_in[4];
  const float* gamma = (const float*)d_in[5];
  const float* beta  = (const float*)d_in[6];
  float* out = (float*)d_out;

  char* ws = (char*)d_ws;
  short* xb   = (short*)ws;  ws += (size_t)8192 * 1024 * 2;
  short* Wb   = (short*)ws;  ws += (size_t)3072 * 1024 * 2;
  short* Wob  = (short*)ws;  ws += (size_t)1024 * 1024 * 2;
  short* qkv  = (short*)ws;  ws += (size_t)8192 * 3072 * 2;
  short* obuf = (short*)ws;  ws += (size_t)8192 * 1024 * 2;
  float* U    = (float*)ws;  ws += (size_t)8192 * 1024 * 4;
  short* VT   = (short*)U;   // aliased: VT dead before U is written

  cvt_bf16<<<4096, 256, 0, stream>>>(x, xb, 8192 * 1024);
  cvt_w<<<2048, 256, 0, stream>>>(W_q, W_k, W_v, W_o, Wb, Wob);

  gemm_bt<1><<<1536, 256, 0, stream>>>(xb, Wb, qkv, 8192, 3072, 1024);
  transpose_v<<<dim3(32, 64), 256, 0, stream>>>(qkv, VT);
  attn_fwd<<<2048, 256, 0, stream>>>(qkv, VT, obuf);
  gemm_bt<0><<<512, 256, 0, stream>>>(obuf, Wob, U, 8192, 1024, 1024);
  resid_ln<<<8192, 256, 0, stream>>>(U, x, gamma, beta, out);
}

// Round 5
// 279.598 us; speedup vs baseline: 1.7715x; 1.0485x over previous
//
#include <hip/hip_runtime.h>
#include <hip/hip_bf16.h>
#include <stdint.h>

typedef __attribute__((ext_vector_type(8))) short bf16x8;
typedef __attribute__((ext_vector_type(4))) float f32x4;

#define GLOBAL_AS __attribute__((address_space(1)))
#define LDS_AS    __attribute__((address_space(3)))

__device__ __forceinline__ void load_lds16(const void* g, void* l) {
  __builtin_amdgcn_global_load_lds((const GLOBAL_AS void*)g, (LDS_AS void*)l, 16, 0, 0);
}

__device__ __forceinline__ float bf2f(short s) {
  return __uint_as_float(((unsigned)(unsigned short)s) << 16);
}
__device__ __forceinline__ short f2bfn(float f) {
  __hip_bfloat16 h = __float2bfloat16(f);
  return __builtin_bit_cast(short, h);
}

// ---------------- fp32 -> bf16 convert: activations ----------------
__global__ __launch_bounds__(256) void cvt_bf16(const float* __restrict__ in,
                                                short* __restrict__ out, int n) {
  int i = (blockIdx.x * 256 + threadIdx.x) * 8;
  if (i >= n) return;
  float4 a = *(const float4*)(in + i);
  float4 b = *(const float4*)(in + i + 4);
  bf16x8 o;
  o[0] = f2bfn(a.x); o[1] = f2bfn(a.y); o[2] = f2bfn(a.z); o[3] = f2bfn(a.w);
  o[4] = f2bfn(b.x); o[5] = f2bfn(b.y); o[6] = f2bfn(b.z); o[7] = f2bfn(b.w);
  *(bf16x8*)(out + i) = o;
}

// ---------------- fp32 -> bf16: all four weight matrices in one launch ------
__global__ __launch_bounds__(256) void cvt_w(const float* __restrict__ q,
                                             const float* __restrict__ k,
                                             const float* __restrict__ v,
                                             const float* __restrict__ o,
                                             short* __restrict__ Wb,
                                             short* __restrict__ Wob) {
  const int sel = blockIdx.x >> 9;          // 0..3
  const int inner = blockIdx.x & 511;
  const int i = (inner * 256 + threadIdx.x) * 8;
  const float* src = sel == 0 ? q : sel == 1 ? k : sel == 2 ? v : o;
  short* dst = sel == 0 ? Wb : sel == 1 ? Wb + 1024 * 1024
             : sel == 2 ? Wb + 2 * 1024 * 1024 : Wob;
  float4 a = *(const float4*)(src + i);
  float4 b = *(const float4*)(src + i + 4);
  bf16x8 ov;
  ov[0] = f2bfn(a.x); ov[1] = f2bfn(a.y); ov[2] = f2bfn(a.z); ov[3] = f2bfn(a.w);
  ov[4] = f2bfn(b.x); ov[5] = f2bfn(b.y); ov[6] = f2bfn(b.z); ov[7] = f2bfn(b.w);
  *(bf16x8*)(dst + i) = ov;
}

// ---------------- C = A * B^T  (A:[M=8192,K] bf16, B:[N,K] bf16) ------------
// grid = 64*NBN (1-D), XCD-swizzled: each XCD owns 8 bm-tiles (2MB A-chunk).
template<int OUT_BF16>
__global__ __launch_bounds__(256) void gemm_bt(const short* __restrict__ A,
                                               const short* __restrict__ B,
                                               void* __restrict__ Cp,
                                               int M, int N, int K) {
  __shared__ short As[128 * 64];
  __shared__ short Bs[128 * 64];
  const int t = threadIdx.x, l = t & 63, w = t >> 6;
  const int g = l >> 4, li = l & 15;
  const int wr = w >> 1, wc = w & 1;
  const int bid = blockIdx.x;
  const int bm = (bid & 7) * 8 + ((bid >> 3) & 7);
  const int bn = bid >> 6;
  f32x4 acc[4][4] = {};
  const size_t arow0 = (size_t)(bm * 128) * K;
  const size_t brow0 = (size_t)(bn * 128) * K;
  for (int k0 = 0; k0 < K; k0 += 64) {
    __syncthreads();
#pragma unroll
    for (int it = 0; it < 4; ++it) {
      int e = it * 2048 + t * 8;
      int r = e >> 6, c = e & 63;
      load_lds16(A + arow0 + (size_t)r * K + (k0 + c), &As[e]);
      load_lds16(B + brow0 + (size_t)r * K + (k0 + c), &Bs[e]);
    }
    __syncthreads();
#pragma unroll
    for (int kk = 0; kk < 2; ++kk) {
      bf16x8 af[4], bfr[4];
#pragma unroll
      for (int m = 0; m < 4; ++m)
        af[m] = *(const bf16x8*)&As[(wr * 64 + m * 16 + li) * 64 + kk * 32 + g * 8];
#pragma unroll
      for (int n = 0; n < 4; ++n)
        bfr[n] = *(const bf16x8*)&Bs[(wc * 64 + n * 16 + li) * 64 + kk * 32 + g * 8];
#pragma unroll
      for (int m = 0; m < 4; ++m)
#pragma unroll
        for (int n = 0; n < 4; ++n)
          acc[m][n] = __builtin_amdgcn_mfma_f32_16x16x32_bf16(af[m], bfr[n], acc[m][n], 0, 0, 0);
    }
  }
#pragma unroll
  for (int m = 0; m < 4; ++m)
#pragma unroll
    for (int n = 0; n < 4; ++n)
#pragma unroll
      for (int r = 0; r < 4; ++r) {
        int row = bm * 128 + wr * 64 + m * 16 + g * 4 + r;
        int col = bn * 128 + wc * 64 + n * 16 + li;
        if (OUT_BF16)
          ((short*)Cp)[(size_t)row * N + col] = f2bfn(acc[m][n][r]);
        else
          ((float*)Cp)[(size_t)row * N + col] = acc[m][n][r];
      }
}

// ---------------- V pre-transpose: qkv V-cols -> VT[bh][d][k] ----------------
__global__ __launch_bounds__(256) void transpose_v(const short* __restrict__ qkv,
                                                   short* __restrict__ VT) {
  const int kt = blockIdx.x;   // 0..31
  const int bh = blockIdx.y;   // 0..63
  const int b = bh >> 4, h = bh & 15;
  __shared__ short T[64][72];
  const int t = threadIdx.x;
  const size_t src = (size_t)b * 2048 * 3072 + 2048 + (size_t)h * 64;
#pragma unroll
  for (int i = 0; i < 2; ++i) {
    int k = i * 32 + (t >> 3);
    int d0 = (t & 7) * 8;
    bf16x8 v = *(const bf16x8*)(qkv + src + (size_t)(kt * 64 + k) * 3072 + d0);
#pragma unroll
    for (int j = 0; j < 8; ++j) T[d0 + j][k] = v[j];
  }
  __syncthreads();
#pragma unroll
  for (int i = 0; i < 2; ++i) {
    int d = i * 32 + (t >> 3);
    int k0 = (t & 7) * 8;
    bf16x8 v = *(const bf16x8*)&T[d][k0];
    *(bf16x8*)(VT + ((size_t)bh * 64 + d) * 2048 + kt * 64 + k0) = v;
  }
}

// ---------------- flash attention (QBLK=128: 4 waves x 32 q-rows) ------------
__global__ __launch_bounds__(256) void attn_fwd(const short* __restrict__ qkv,
                                                const short* __restrict__ VT,
                                                short* __restrict__ obuf) {
  const int f0 = blockIdx.x;                 // 1024 blocks
  const int work = (f0 & 7) * 128 + (f0 >> 3);
  const int qt = work & 15;                  // 16 q-tiles of 128 rows
  const int bh = work >> 4;                  // 0..63
  const int b = bh >> 4, h = bh & 15;
  const int t = threadIdx.x, w = t >> 6, l = t & 63;
  const int g = l >> 4, li = l & 15;

  __shared__ short Ks[2][64 * 64];           // K tile [key][d], swizzled, dbuf
  __shared__ short Vts[2][64 * 64];          // V^T tile [d][key], swizzled, dbuf
  __shared__ short Ps[4][32 * 72];           // per-wave P [q(32)][key], stride 72

  const size_t base = (size_t)b * 2048 * 3072 + (size_t)h * 64;
  const short* Vsrc = VT + (size_t)bh * 64 * 2048;

  // Q fragments for 2 q-halves, pre-scaled by 0.125*log2(e) (exp2 domain)
  bf16x8 qf[2][2];
  {
    const float QSC = 0.125f * 1.44269504088896341f;
#pragma unroll
    for (int qh = 0; qh < 2; ++qh) {
      const short* qp = qkv + base + (size_t)(qt * 128 + w * 32 + qh * 16 + li) * 3072;
#pragma unroll
      for (int c = 0; c < 2; ++c) {
        bf16x8 v = *(const bf16x8*)(qp + c * 32 + g * 8);
#pragma unroll
        for (int i = 0; i < 8; ++i) v[i] = f2bfn(bf2f(v[i]) * QSC);
        qf[qh][c] = v;
      }
    }
  }

  bf16x8 ones;
#pragma unroll
  for (int i = 0; i < 8; ++i) ones[i] = (short)0x3F80;  // bf16 1.0

  float m_[2] = {-1e30f, -1e30f};
  f32x4 o_[2][4], lacc[2];
#pragma unroll
  for (int qh = 0; qh < 2; ++qh) {
#pragma unroll
    for (int dj = 0; dj < 4; ++dj) o_[qh][dj] = (f32x4){0.f, 0.f, 0.f, 0.f};
    lacc[qh] = (f32x4){0.f, 0.f, 0.f, 0.f};
  }

  const int sw = li & 7;

#define STAGE(buf, kt_)                                                          \
  {                                                                              \
    _Pragma("unroll")                                                            \
    for (int it = 0; it < 2; ++it) {                                             \
      int e = it * 2048 + t * 8;                                                 \
      int r = e >> 6;                                                            \
      int cs = (e >> 3) & 7;                                                     \
      int cg = cs ^ (r & 7);                                                     \
      load_lds16(qkv + base + 1024 + (size_t)((kt_) * 64 + r) * 3072 + cg * 8,   \
                 &Ks[buf][e]);                                                   \
      load_lds16(Vsrc + (size_t)r * 2048 + (kt_) * 64 + cg * 8, &Vts[buf][e]);   \
    }                                                                            \
  }

  STAGE(0, 0);
  asm volatile("s_waitcnt vmcnt(0)" ::: "memory");
  __syncthreads();

  for (int kt = 0; kt < 32; ++kt) {
    const int cur = kt & 1;
    if (kt + 1 < 32) STAGE(cur ^ 1, kt + 1);

    // S^T = K (Q scaled)^T for both q-halves: key = j*16+g*4+r, q = li
    f32x4 s_[2][4];
#pragma unroll
    for (int qh = 0; qh < 2; ++qh)
#pragma unroll
      for (int j = 0; j < 4; ++j) s_[qh][j] = (f32x4){0.f, 0.f, 0.f, 0.f};
    __builtin_amdgcn_s_setprio(1);
#pragma unroll
    for (int c = 0; c < 2; ++c)
#pragma unroll
      for (int j = 0; j < 4; ++j) {
        bf16x8 kf = *(const bf16x8*)&Ks[cur][(j * 16 + li) * 64 + (((c * 4 + g) ^ sw) * 8)];
        s_[0][j] = __builtin_amdgcn_mfma_f32_16x16x32_bf16(kf, qf[0][c], s_[0][j], 0, 0, 0);
        s_[1][j] = __builtin_amdgcn_mfma_f32_16x16x32_bf16(kf, qf[1][c], s_[1][j], 0, 0, 0);
      }
    __builtin_amdgcn_s_setprio(0);

    // tile max per q-half (max3-friendly), 2 cross-g shuffles each
    float mt[2];
#pragma unroll
    for (int qh = 0; qh < 2; ++qh) {
      float m0 = fmaxf(fmaxf(s_[qh][0][0], s_[qh][0][1]), s_[qh][0][2]);
      m0 = fmaxf(fmaxf(m0, s_[qh][0][3]), s_[qh][1][0]);
      m0 = fmaxf(fmaxf(m0, s_[qh][1][1]), s_[qh][1][2]);
      m0 = fmaxf(fmaxf(m0, s_[qh][1][3]), s_[qh][2][0]);
      m0 = fmaxf(fmaxf(m0, s_[qh][2][1]), s_[qh][2][2]);
      m0 = fmaxf(fmaxf(m0, s_[qh][2][3]), s_[qh][3][0]);
      m0 = fmaxf(fmaxf(m0, s_[qh][3][1]), s_[qh][3][2]);
      m0 = fmaxf(m0, s_[qh][3][3]);
      m0 = fmaxf(m0, __shfl_xor(m0, 16));
      m0 = fmaxf(m0, __shfl_xor(m0, 32));
      mt[qh] = m0;
    }

    // defer-max (log2 domain, THR=8)
    bool ok = (mt[0] <= m_[0] + 8.f) && (mt[1] <= m_[1] + 8.f);
    if (!__all(ok)) {
#pragma unroll
      for (int qh = 0; qh < 2; ++qh) {
        float mn = fmaxf(m_[qh], mt[qh]);
        float al = exp2f(m_[qh] - mn);
        m_[qh] = mn;
#pragma unroll
        for (int r = 0; r < 4; ++r) {
          float alr = __shfl(al, (l & 48) | (g * 4 + r));
#pragma unroll
          for (int dj = 0; dj < 4; ++dj) o_[qh][dj][r] *= alr;
          lacc[qh][r] *= alr;
        }
      }
    }

    // P = exp2(S - m), pack via v_cvt_pk, one b64 write per (qh,j)
#pragma unroll
    for (int qh = 0; qh < 2; ++qh)
#pragma unroll
      for (int j = 0; j < 4; ++j) {
        float p0 = exp2f(s_[qh][j][0] - m_[qh]);
        float p1 = exp2f(s_[qh][j][1] - m_[qh]);
        float p2 = exp2f(s_[qh][j][2] - m_[qh]);
        float p3 = exp2f(s_[qh][j][3] - m_[qh]);
        unsigned u0, u1;
        asm("v_cvt_pk_bf16_f32 %0, %1, %2" : "=v"(u0) : "v"(p0), "v"(p1));
        asm("v_cvt_pk_bf16_f32 %0, %1, %2" : "=v"(u1) : "v"(p2), "v"(p3));
        uint2 pk2; pk2.x = u0; pk2.y = u1;
        *(uint2*)&Ps[w][(qh * 16 + li) * 72 + j * 16 + g * 4] = pk2;
      }
    asm volatile("s_waitcnt lgkmcnt(0)" ::: "memory");

    // O += P V ; l += P * ones  (vb reads shared across both q-halves)
    __builtin_amdgcn_s_setprio(1);
#pragma unroll
    for (int c = 0; c < 2; ++c) {
      bf16x8 pa0 = *(const bf16x8*)&Ps[w][li * 72 + c * 32 + g * 8];
      bf16x8 pa1 = *(const bf16x8*)&Ps[w][(16 + li) * 72 + c * 32 + g * 8];
      lacc[0] = __builtin_amdgcn_mfma_f32_16x16x32_bf16(pa0, ones, lacc[0], 0, 0, 0);
      lacc[1] = __builtin_amdgcn_mfma_f32_16x16x32_bf16(pa1, ones, lacc[1], 0, 0, 0);
#pragma unroll
      for (int dj = 0; dj < 4; ++dj) {
        bf16x8 vb = *(const bf16x8*)&Vts[cur][(dj * 16 + li) * 64 + (((c * 4 + g) ^ sw) * 8)];
        o_[0][dj] = __builtin_amdgcn_mfma_f32_16x16x32_bf16(pa0, vb, o_[0][dj], 0, 0, 0);
        o_[1][dj] = __builtin_amdgcn_mfma_f32_16x16x32_bf16(pa1, vb, o_[1][dj], 0, 0, 0);
      }
    }
    __builtin_amdgcn_s_setprio(0);

    asm volatile("s_waitcnt vmcnt(0)" ::: "memory");
    __syncthreads();
  }

  // epilogue: lacc already in O row layout -> no shuffles
#pragma unroll
  for (int qh = 0; qh < 2; ++qh)
#pragma unroll
    for (int r = 0; r < 4; ++r) {
      float ilr = 1.f / lacc[qh][r];
      int row = b * 2048 + qt * 128 + w * 32 + qh * 16 + g * 4 + r;
#pragma unroll
      for (int dj = 0; dj < 4; ++dj) {
        int col = h * 64 + dj * 16 + li;
        obuf[(size_t)row * 1024 + col] = f2bfn(o_[qh][dj][r] * ilr);
      }
    }
#undef STAGE
}

// ---------------- residual + LayerNorm (fp32, float4) ----------------
__global__ __launch_bounds__(256) void resid_ln(const float* __restrict__ U,
                                                const float* __restrict__ x,
                                                const float* __restrict__ gamma,
                                                const float* __restrict__ beta,
                                                float* __restrict__ out) {
  const int row = blockIdx.x;
  const int t = threadIdx.x, w = t >> 6, l = t & 63;
  const float4 uu = *(const float4*)(U + (size_t)row * 1024 + t * 4);
  const float4 xx = *(const float4*)(x + (size_t)row * 1024 + t * 4);
  float y[4] = {uu.x + xx.x, uu.y + xx.y, uu.z + xx.z, uu.w + xx.w};
  float s = (y[0] + y[1]) + (y[2] + y[3]);
#pragma unroll
  for (int d = 1; d < 64; d <<= 1) s += __shfl_xor(s, d);
  __shared__ float red[4];
  if (l == 0) red[w] = s;
  __syncthreads();
  s = red[0] + red[1] + red[2] + red[3];
  const float mu = s * (1.f / 1024.f);
  float vs = 0.f;
#pragma unroll
  for (int i = 0; i < 4; ++i) { float d0 = y[i] - mu; vs += d0 * d0; }
#pragma unroll
  for (int d = 1; d < 64; d <<= 1) vs += __shfl_xor(vs, d);
  __syncthreads();
  if (l == 0) red[w] = vs;
  __syncthreads();
  vs = red[0] + red[1] + red[2] + red[3];
  const float rstd = rsqrtf(vs * (1.f / 1024.f) + 1e-5f);
  const float4 gg = *(const float4*)(gamma + t * 4);
  const float4 bb = *(const float4*)(beta + t * 4);
  float4 oo;
  oo.x = (y[0] - mu) * rstd * gg.x + bb.x;
  oo.y = (y[1] - mu) * rstd * gg.y + bb.y;
  oo.z = (y[2] - mu) * rstd * gg.z + bb.z;
  oo.w = (y[3] - mu) * rstd * gg.w + bb.w;
  *(float4*)(out + (size_t)row * 1024 + t * 4) = oo;
}

extern "C" void kernel_launch(void* const* d_in, const int* in_sizes, int n_in,
                              void* d_out, int out_size, void* d_ws, size_t ws_size,
                              hipStream_t stream) {
  const float* x     = (const float*)d_in[0];
  const float* W_q   = (const float*)d_in[1];
  const float* W_k   = (const float*)d_in[2];
  const float* W_v   = (const float*)d_in[3];
  const float* W_o   = (const float*)d_in[4];
  const float* gamma = (const float*)d_in[5];
  const float* beta  = (const float*)d_in[6];
  float* out = (float*)d_out;

  char* ws = (char*)d_ws;
  short* xb   = (short*)ws;  ws += (size_t)8192 * 1024 * 2;
  short* Wb   = (short*)ws;  ws += (size_t)3072 * 1024 * 2;
  short* Wob  = (short*)ws;  ws += (size_t)1024 * 1024 * 2;
  short* qkv  = (short*)ws;  ws += (size_t)8192 * 3072 * 2;
  short* obuf = (short*)ws;  ws += (size_t)8192 * 1024 * 2;
  float* U    = (float*)ws;  ws += (size_t)8192 * 1024 * 4;
  short* VT   = (short*)U;   // aliased: VT dead before U is written

  cvt_bf16<<<4096, 256, 0, stream>>>(x, xb, 8192 * 1024);
  cvt_w<<<2048, 256, 0, stream>>>(W_q, W_k, W_v, W_o, Wb, Wob);

  gemm_bt<1><<<1536, 256, 0, stream>>>(xb, Wb, qkv, 8192, 3072, 1024);
  transpose_v<<<dim3(32, 64), 256, 0, stream>>>(qkv, VT);
  attn_fwd<<<1024, 256, 0, stream>>>(qkv, VT, obuf);
  gemm_bt<0><<<512, 256, 0, stream>>>(obuf, Wob, U, 8192, 1024, 1024);
  resid_ln<<<8192, 256, 0, stream>>>(U, x, gamma, beta, out);
}

// Round 6
// 262.623 us; speedup vs baseline: 1.8860x; 1.0646x over previous
//
#include <hip/hip_runtime.h>
#include <hip/hip_bf16.h>
#include <stdint.h>

typedef __attribute__((ext_vector_type(8))) short bf16x8;
typedef __attribute__((ext_vector_type(4))) float f32x4;

#define GLOBAL_AS __attribute__((address_space(1)))
#define LDS_AS    __attribute__((address_space(3)))

__device__ __forceinline__ void load_lds16(const void* g, void* l) {
  __builtin_amdgcn_global_load_lds((const GLOBAL_AS void*)g, (LDS_AS void*)l, 16, 0, 0);
}

__device__ __forceinline__ float bf2f(short s) {
  return __uint_as_float(((unsigned)(unsigned short)s) << 16);
}
__device__ __forceinline__ short f2bfn(float f) {
  __hip_bfloat16 h = __float2bfloat16(f);
  return __builtin_bit_cast(short, h);
}

// ---------------- fp32 -> bf16 convert: activations ----------------
__global__ __launch_bounds__(256) void cvt_bf16(const float* __restrict__ in,
                                                short* __restrict__ out, int n) {
  int i = (blockIdx.x * 256 + threadIdx.x) * 8;
  if (i >= n) return;
  float4 a = *(const float4*)(in + i);
  float4 b = *(const float4*)(in + i + 4);
  bf16x8 o;
  o[0] = f2bfn(a.x); o[1] = f2bfn(a.y); o[2] = f2bfn(a.z); o[3] = f2bfn(a.w);
  o[4] = f2bfn(b.x); o[5] = f2bfn(b.y); o[6] = f2bfn(b.z); o[7] = f2bfn(b.w);
  *(bf16x8*)(out + i) = o;
}

// ---------------- fp32 -> bf16: all four weight matrices in one launch ------
__global__ __launch_bounds__(256) void cvt_w(const float* __restrict__ q,
                                             const float* __restrict__ k,
                                             const float* __restrict__ v,
                                             const float* __restrict__ o,
                                             short* __restrict__ Wb,
                                             short* __restrict__ Wob) {
  const int sel = blockIdx.x >> 9;          // 0..3
  const int inner = blockIdx.x & 511;
  const int i = (inner * 256 + threadIdx.x) * 8;
  const float* src = sel == 0 ? q : sel == 1 ? k : sel == 2 ? v : o;
  short* dst = sel == 0 ? Wb : sel == 1 ? Wb + 1024 * 1024
             : sel == 2 ? Wb + 2 * 1024 * 1024 : Wob;
  float4 a = *(const float4*)(src + i);
  float4 b = *(const float4*)(src + i + 4);
  bf16x8 ov;
  ov[0] = f2bfn(a.x); ov[1] = f2bfn(a.y); ov[2] = f2bfn(a.z); ov[3] = f2bfn(a.w);
  ov[4] = f2bfn(b.x); ov[5] = f2bfn(b.y); ov[6] = f2bfn(b.z); ov[7] = f2bfn(b.w);
  *(bf16x8*)(dst + i) = ov;
}

// ---------------- C = A * B^T  (A:[M=8192,K] bf16, B:[N,K] bf16) ------------
// grid = 64*NBN (1-D), XCD-swizzled: each XCD owns 8 bm-tiles (2MB A-chunk).
template<int OUT_BF16>
__global__ __launch_bounds__(256) void gemm_bt(const short* __restrict__ A,
                                               const short* __restrict__ B,
                                               void* __restrict__ Cp,
                                               int M, int N, int K) {
  __shared__ short As[128 * 64];
  __shared__ short Bs[128 * 64];
  const int t = threadIdx.x, l = t & 63, w = t >> 6;
  const int g = l >> 4, li = l & 15;
  const int wr = w >> 1, wc = w & 1;
  const int bid = blockIdx.x;
  const int bm = (bid & 7) * 8 + ((bid >> 3) & 7);
  const int bn = bid >> 6;
  f32x4 acc[4][4] = {};
  const size_t arow0 = (size_t)(bm * 128) * K;
  const size_t brow0 = (size_t)(bn * 128) * K;
  for (int k0 = 0; k0 < K; k0 += 64) {
    __syncthreads();
#pragma unroll
    for (int it = 0; it < 4; ++it) {
      int e = it * 2048 + t * 8;
      int r = e >> 6, c = e & 63;
      load_lds16(A + arow0 + (size_t)r * K + (k0 + c), &As[e]);
      load_lds16(B + brow0 + (size_t)r * K + (k0 + c), &Bs[e]);
    }
    __syncthreads();
#pragma unroll
    for (int kk = 0; kk < 2; ++kk) {
      bf16x8 af[4], bfr[4];
#pragma unroll
      for (int m = 0; m < 4; ++m)
        af[m] = *(const bf16x8*)&As[(wr * 64 + m * 16 + li) * 64 + kk * 32 + g * 8];
#pragma unroll
      for (int n = 0; n < 4; ++n)
        bfr[n] = *(const bf16x8*)&Bs[(wc * 64 + n * 16 + li) * 64 + kk * 32 + g * 8];
#pragma unroll
      for (int m = 0; m < 4; ++m)
#pragma unroll
        for (int n = 0; n < 4; ++n)
          acc[m][n] = __builtin_amdgcn_mfma_f32_16x16x32_bf16(af[m], bfr[n], acc[m][n], 0, 0, 0);
    }
  }
#pragma unroll
  for (int m = 0; m < 4; ++m)
#pragma unroll
    for (int n = 0; n < 4; ++n)
#pragma unroll
      for (int r = 0; r < 4; ++r) {
        int row = bm * 128 + wr * 64 + m * 16 + g * 4 + r;
        int col = bn * 128 + wc * 64 + n * 16 + li;
        if (OUT_BF16)
          ((short*)Cp)[(size_t)row * N + col] = f2bfn(acc[m][n][r]);
        else
          ((float*)Cp)[(size_t)row * N + col] = acc[m][n][r];
      }
}

// ---------------- V pre-transpose: qkv V-cols -> VT[bh][d][k] ----------------
__global__ __launch_bounds__(256) void transpose_v(const short* __restrict__ qkv,
                                                   short* __restrict__ VT) {
  const int kt = blockIdx.x;   // 0..31
  const int bh = blockIdx.y;   // 0..63
  const int b = bh >> 4, h = bh & 15;
  __shared__ short T[64][72];
  const int t = threadIdx.x;
  const size_t src = (size_t)b * 2048 * 3072 + 2048 + (size_t)h * 64;
#pragma unroll
  for (int i = 0; i < 2; ++i) {
    int k = i * 32 + (t >> 3);
    int d0 = (t & 7) * 8;
    bf16x8 v = *(const bf16x8*)(qkv + src + (size_t)(kt * 64 + k) * 3072 + d0);
#pragma unroll
    for (int j = 0; j < 8; ++j) T[d0 + j][k] = v[j];
  }
  __syncthreads();
#pragma unroll
  for (int i = 0; i < 2; ++i) {
    int d = i * 32 + (t >> 3);
    int k0 = (t & 7) * 8;
    bf16x8 v = *(const bf16x8*)&T[d][k0];
    *(bf16x8*)(VT + ((size_t)bh * 64 + d) * 2048 + kt * 64 + k0) = v;
  }
}

// ---------------- flash attention (QBLK=128: 4 waves x 32 q-rows) ------------
// LDS = K dbuf 16K + V dbuf 16K + Ps 8K = 40960 B -> exactly 4 blocks/CU.
__global__ __launch_bounds__(256, 4) void attn_fwd(const short* __restrict__ qkv,
                                                   const short* __restrict__ VT,
                                                   short* __restrict__ obuf) {
  const int f0 = blockIdx.x;                 // 1024 blocks
  const int work = (f0 & 7) * 128 + (f0 >> 3);
  const int qt = work & 15;                  // 16 q-tiles of 128 rows
  const int bh = work >> 4;                  // 0..63
  const int b = bh >> 4, h = bh & 15;
  const int t = threadIdx.x, w = t >> 6, l = t & 63;
  const int g = l >> 4, li = l & 15;

  __shared__ short Ks[2][64 * 64];           // K tile [key][d], swizzled, dbuf
  __shared__ short Vts[2][64 * 64];          // V^T tile [d][key], swizzled, dbuf
  __shared__ short Ps[4][16 * 64];           // per-wave P [q(16)][key], XOR-swz

  const size_t base = (size_t)b * 2048 * 3072 + (size_t)h * 64;
  const short* Vsrc = VT + (size_t)bh * 64 * 2048;

  // Q fragments for 2 q-halves, pre-scaled by 0.125*log2(e) (exp2 domain)
  bf16x8 qf[2][2];
  {
    const float QSC = 0.125f * 1.44269504088896341f;
#pragma unroll
    for (int qh = 0; qh < 2; ++qh) {
      const short* qp = qkv + base + (size_t)(qt * 128 + w * 32 + qh * 16 + li) * 3072;
#pragma unroll
      for (int c = 0; c < 2; ++c) {
        bf16x8 v = *(const bf16x8*)(qp + c * 32 + g * 8);
#pragma unroll
        for (int i = 0; i < 8; ++i) v[i] = f2bfn(bf2f(v[i]) * QSC);
        qf[qh][c] = v;
      }
    }
  }

  bf16x8 ones;
#pragma unroll
  for (int i = 0; i < 8; ++i) ones[i] = (short)0x3F80;  // bf16 1.0

  float m_[2] = {-1e30f, -1e30f};
  f32x4 o_[2][4], lacc[2];
#pragma unroll
  for (int qh = 0; qh < 2; ++qh) {
#pragma unroll
    for (int dj = 0; dj < 4; ++dj) o_[qh][dj] = (f32x4){0.f, 0.f, 0.f, 0.f};
    lacc[qh] = (f32x4){0.f, 0.f, 0.f, 0.f};
  }

  const int sw = li & 7;

#define STAGE(buf, kt_)                                                          \
  {                                                                              \
    _Pragma("unroll")                                                            \
    for (int it = 0; it < 2; ++it) {                                             \
      int e = it * 2048 + t * 8;                                                 \
      int r = e >> 6;                                                            \
      int cs = (e >> 3) & 7;                                                     \
      int cg = cs ^ (r & 7);                                                     \
      load_lds16(qkv + base + 1024 + (size_t)((kt_) * 64 + r) * 3072 + cg * 8,   \
                 &Ks[buf][e]);                                                   \
      load_lds16(Vsrc + (size_t)r * 2048 + (kt_) * 64 + cg * 8, &Vts[buf][e]);   \
    }                                                                            \
  }

  STAGE(0, 0);
  asm volatile("s_waitcnt vmcnt(0)" ::: "memory");
  __syncthreads();

  for (int kt = 0; kt < 32; ++kt) {
    const int cur = kt & 1;
    if (kt + 1 < 32) STAGE(cur ^ 1, kt + 1);

    // S^T = K (Q scaled)^T for both q-halves: key = j*16+g*4+r, q = li
    f32x4 s_[2][4];
#pragma unroll
    for (int qh = 0; qh < 2; ++qh)
#pragma unroll
      for (int j = 0; j < 4; ++j) s_[qh][j] = (f32x4){0.f, 0.f, 0.f, 0.f};
    __builtin_amdgcn_s_setprio(1);
#pragma unroll
    for (int c = 0; c < 2; ++c)
#pragma unroll
      for (int j = 0; j < 4; ++j) {
        bf16x8 kf = *(const bf16x8*)&Ks[cur][(j * 16 + li) * 64 + (((c * 4 + g) ^ sw) * 8)];
        s_[0][j] = __builtin_amdgcn_mfma_f32_16x16x32_bf16(kf, qf[0][c], s_[0][j], 0, 0, 0);
        s_[1][j] = __builtin_amdgcn_mfma_f32_16x16x32_bf16(kf, qf[1][c], s_[1][j], 0, 0, 0);
      }
    __builtin_amdgcn_s_setprio(0);

    // tile max per q-half: balanced max3 tree (depth 3), 2 cross-g shuffles
    float mt[2];
#pragma unroll
    for (int qh = 0; qh < 2; ++qh) {
      float a0 = fmaxf(fmaxf(s_[qh][0][0], s_[qh][0][1]), s_[qh][0][2]);
      float a1 = fmaxf(fmaxf(s_[qh][0][3], s_[qh][1][0]), s_[qh][1][1]);
      float a2 = fmaxf(fmaxf(s_[qh][1][2], s_[qh][1][3]), s_[qh][2][0]);
      float a3 = fmaxf(fmaxf(s_[qh][2][1], s_[qh][2][2]), s_[qh][2][3]);
      float a4 = fmaxf(fmaxf(s_[qh][3][0], s_[qh][3][1]), s_[qh][3][2]);
      float b0 = fmaxf(fmaxf(a0, a1), a2);
      float b1 = fmaxf(fmaxf(a3, a4), s_[qh][3][3]);
      float m0 = fmaxf(b0, b1);
      m0 = fmaxf(m0, __shfl_xor(m0, 16));
      m0 = fmaxf(m0, __shfl_xor(m0, 32));
      mt[qh] = m0;
    }

    // defer-max (log2 domain, THR=8)
    bool ok = (mt[0] <= m_[0] + 8.f) && (mt[1] <= m_[1] + 8.f);
    if (!__all(ok)) {
#pragma unroll
      for (int qh = 0; qh < 2; ++qh) {
        float mn = fmaxf(m_[qh], mt[qh]);
        float al = exp2f(m_[qh] - mn);
        m_[qh] = mn;
#pragma unroll
        for (int r = 0; r < 4; ++r) {
          float alr = __shfl(al, (l & 48) | (g * 4 + r));
#pragma unroll
          for (int dj = 0; dj < 4; ++dj) o_[qh][dj][r] *= alr;
          lacc[qh][r] *= alr;
        }
      }
    }

    // per q-half: P = exp2(S-m) -> bf16 pack -> XOR-swz Ps -> PV
    // (single shared Ps buffer; wave-local in-order DS makes the reuse safe)
#pragma unroll
    for (int qh = 0; qh < 2; ++qh) {
#pragma unroll
      for (int j = 0; j < 4; ++j) {
        float p0 = exp2f(s_[qh][j][0] - m_[qh]);
        float p1 = exp2f(s_[qh][j][1] - m_[qh]);
        float p2 = exp2f(s_[qh][j][2] - m_[qh]);
        float p3 = exp2f(s_[qh][j][3] - m_[qh]);
        unsigned u0, u1;
        asm("v_cvt_pk_bf16_f32 %0, %1, %2" : "=v"(u0) : "v"(p0), "v"(p1));
        asm("v_cvt_pk_bf16_f32 %0, %1, %2" : "=v"(u1) : "v"(p2), "v"(p3));
        uint2 pk2; pk2.x = u0; pk2.y = u1;
        int pos = (j * 16 + g * 4) ^ (sw << 3);   // XOR-swz, keeps 4-contig
        *(uint2*)&Ps[w][li * 64 + pos] = pk2;
      }
      asm volatile("s_waitcnt lgkmcnt(0)" ::: "memory");

      __builtin_amdgcn_s_setprio(1);
#pragma unroll
      for (int c = 0; c < 2; ++c) {
        bf16x8 pa = *(const bf16x8*)&Ps[w][li * 64 + (((c * 4 + g) ^ sw) * 8)];
        lacc[qh] = __builtin_amdgcn_mfma_f32_16x16x32_bf16(pa, ones, lacc[qh], 0, 0, 0);
#pragma unroll
        for (int dj = 0; dj < 4; ++dj) {
          bf16x8 vb = *(const bf16x8*)&Vts[cur][(dj * 16 + li) * 64 + (((c * 4 + g) ^ sw) * 8)];
          o_[qh][dj] = __builtin_amdgcn_mfma_f32_16x16x32_bf16(pa, vb, o_[qh][dj], 0, 0, 0);
        }
      }
      __builtin_amdgcn_s_setprio(0);
    }

    asm volatile("s_waitcnt vmcnt(0)" ::: "memory");
    __syncthreads();
  }

  // epilogue: lacc already in O row layout -> no shuffles
#pragma unroll
  for (int qh = 0; qh < 2; ++qh)
#pragma unroll
    for (int r = 0; r < 4; ++r) {
      float ilr = 1.f / lacc[qh][r];
      int row = b * 2048 + qt * 128 + w * 32 + qh * 16 + g * 4 + r;
#pragma unroll
      for (int dj = 0; dj < 4; ++dj) {
        int col = h * 64 + dj * 16 + li;
        obuf[(size_t)row * 1024 + col] = f2bfn(o_[qh][dj][r] * ilr);
      }
    }
#undef STAGE
}

// ---------------- residual + LayerNorm (fp32, float4) ----------------
__global__ __launch_bounds__(256) void resid_ln(const float* __restrict__ U,
                                                const float* __restrict__ x,
                                                const float* __restrict__ gamma,
                                                const float* __restrict__ beta,
                                                float* __restrict__ out) {
  const int row = blockIdx.x;
  const int t = threadIdx.x, w = t >> 6, l = t & 63;
  const float4 uu = *(const float4*)(U + (size_t)row * 1024 + t * 4);
  const float4 xx = *(const float4*)(x + (size_t)row * 1024 + t * 4);
  float y[4] = {uu.x + xx.x, uu.y + xx.y, uu.z + xx.z, uu.w + xx.w};
  float s = (y[0] + y[1]) + (y[2] + y[3]);
#pragma unroll
  for (int d = 1; d < 64; d <<= 1) s += __shfl_xor(s, d);
  __shared__ float red[4];
  if (l == 0) red[w] = s;
  __syncthreads();
  s = red[0] + red[1] + red[2] + red[3];
  const float mu = s * (1.f / 1024.f);
  float vs = 0.f;
#pragma unroll
  for (int i = 0; i < 4; ++i) { float d0 = y[i] - mu; vs += d0 * d0; }
#pragma unroll
  for (int d = 1; d < 64; d <<= 1) vs += __shfl_xor(vs, d);
  __syncthreads();
  if (l == 0) red[w] = vs;
  __syncthreads();
  vs = red[0] + red[1] + red[2] + red[3];
  const float rstd = rsqrtf(vs * (1.f / 1024.f) + 1e-5f);
  const float4 gg = *(const float4*)(gamma + t * 4);
  const float4 bb = *(const float4*)(beta + t * 4);
  float4 oo;
  oo.x = (y[0] - mu) * rstd * gg.x + bb.x;
  oo.y = (y[1] - mu) * rstd * gg.y + bb.y;
  oo.z = (y[2] - mu) * rstd * gg.z + bb.z;
  oo.w = (y[3] - mu) * rstd * gg.w + bb.w;
  *(float4*)(out + (size_t)row * 1024 + t * 4) = oo;
}

extern "C" void kernel_launch(void* const* d_in, const int* in_sizes, int n_in,
                              void* d_out, int out_size, void* d_ws, size_t ws_size,
                              hipStream_t stream) {
  const float* x     = (const float*)d_in[0];
  const float* W_q   = (const float*)d_in[1];
  const float* W_k   = (const float*)d_in[2];
  const float* W_v   = (const float*)d_in[3];
  const float* W_o   = (const float*)d_in[4];
  const float* gamma = (const float*)d_in[5];
  const float* beta  = (const float*)d_in[6];
  float* out = (float*)d_out;

  char* ws = (char*)d_ws;
  short* xb   = (short*)ws;  ws += (size_t)8192 * 1024 * 2;
  short* Wb   = (short*)ws;  ws += (size_t)3072 * 1024 * 2;
  short* Wob  = (short*)ws;  ws += (size_t)1024 * 1024 * 2;
  short* qkv  = (short*)ws;  ws += (size_t)8192 * 3072 * 2;
  short* obuf = (short*)ws;  ws += (size_t)8192 * 1024 * 2;
  float* U    = (float*)ws;  ws += (size_t)8192 * 1024 * 4;
  short* VT   = (short*)U;   // aliased: VT dead before U is written

  cvt_bf16<<<4096, 256, 0, stream>>>(x, xb, 8192 * 1024);
  cvt_w<<<2048, 256, 0, stream>>>(W_q, W_k, W_v, W_o, Wb, Wob);

  gemm_bt<1><<<1536, 256, 0, stream>>>(xb, Wb, qkv, 8192, 3072, 1024);
  transpose_v<<<dim3(32, 64), 256, 0, stream>>>(qkv, VT);
  attn_fwd<<<1024, 256, 0, stream>>>(qkv, VT, obuf);
  gemm_bt<0><<<512, 256, 0, stream>>>(obuf, Wob, U, 8192, 1024, 1024);
  resid_ln<<<8192, 256, 0, stream>>>(U, x, gamma, beta, out);
}